// Round 1
// baseline (8497.288 us; speedup 1.0000x reference)
//
#include <hip/hip_runtime.h>
#include <hip/hip_bf16.h>

// ---------------------------------------------------------------------------
// Transformer (enc-dec) forward, fp32 baseline.
// B=8, S=512, D=512, H=8, DK=64, DFF=2048, L=6, IN=4096, OUT=1000
// ---------------------------------------------------------------------------

#define DM 512
#define NH 8
#define DK 64
#define SEQ 512
#define NB 8
#define NL 6
#define DFF 2048
#define OUTD 1000
#define EMB_SCALE 22.627416997969522f  // sqrt(512)
#define PE_C (-0.017988946039015984)   // -ln(10000)/512

// ---------------- embedding + positional encoding ----------------
__global__ __launch_bounds__(256) void embed_enc(const int* __restrict__ x,
                                                 const float* __restrict__ emb,
                                                 float* __restrict__ e) {
  int idx = blockIdx.x * 256 + threadIdx.x;     // over NB*SEQ*DM
  int d = idx & (DM - 1);
  int bs = idx >> 9;                            // b*SEQ + s
  int s = bs & (SEQ - 1);
  int tok = x[bs];
  double div = exp((double)(d & ~1) * PE_C);
  double arg = (double)s * div;
  float pe = (d & 1) ? (float)cos(arg) : (float)sin(arg);
  e[idx] = emb[(size_t)tok * DM + d] * EMB_SCALE + pe;
}

__global__ __launch_bounds__(256) void embed_dec(const int* __restrict__ t,
                                                 const float* __restrict__ emb,
                                                 float* __restrict__ dd) {
  int idx = blockIdx.x * 256 + threadIdx.x;     // over NB*DM
  int d = idx & (DM - 1);
  int b = idx >> 9;
  float pe = (d & 1) ? 1.0f : 0.0f;             // PE row 0
  dd[idx] = emb[(size_t)t[b] * DM + d] * EMB_SCALE + pe;
}

// ---------------- tiled GEMM: C = A @ W + bias, optional relu --------------
// A[M,K] row-major, W[K,N] row-major. z-batched over (W,bias,C) strides.
#define GBM 64
#define GBN 64
#define GBK 16
template <bool RELU>
__global__ __launch_bounds__(256) void gemm_bias(
    const float* __restrict__ A, const float* __restrict__ W,
    const float* __restrict__ bias, float* __restrict__ C,
    int M, int N, int K, long wStride, long bStride, long cStride) {
  int z = blockIdx.z;
  W += (size_t)z * wStride;
  bias += (size_t)z * bStride;
  C += (size_t)z * cStride;

  __shared__ float As[GBK][GBM + 4];
  __shared__ float Bs[GBK][GBN + 4];

  int tid = threadIdx.x;
  int tx = tid & 15;        // n-dir (x4)
  int ty = tid >> 4;        // m-dir (x4)
  int m0 = blockIdx.y * GBM;
  int n0 = blockIdx.x * GBN;

  int la_m = tid >> 2;             // 0..63
  int la_k = (tid & 3) * 4;        // 0,4,8,12
  int lb_k = tid >> 4;             // 0..15
  int lb_n = (tid & 15) * 4;

  float acc[4][4] = {};

  for (int k0 = 0; k0 < K; k0 += GBK) {
    {
      int gm = m0 + la_m;
      float4 av = make_float4(0.f, 0.f, 0.f, 0.f);
      if (gm < M) av = *(const float4*)(A + (size_t)gm * K + k0 + la_k);
      As[la_k + 0][la_m] = av.x;
      As[la_k + 1][la_m] = av.y;
      As[la_k + 2][la_m] = av.z;
      As[la_k + 3][la_m] = av.w;
    }
    {
      int gn = n0 + lb_n;
      float4 bv = make_float4(0.f, 0.f, 0.f, 0.f);
      if (gn < N) bv = *(const float4*)(W + (size_t)(k0 + lb_k) * N + gn);
      *(float4*)&Bs[lb_k][lb_n] = bv;
    }
    __syncthreads();
#pragma unroll
    for (int kk = 0; kk < GBK; ++kk) {
      float4 a4 = *(const float4*)&As[kk][ty * 4];
      float4 b4 = *(const float4*)&Bs[kk][tx * 4];
      float av[4] = {a4.x, a4.y, a4.z, a4.w};
      float bv[4] = {b4.x, b4.y, b4.z, b4.w};
#pragma unroll
      for (int i = 0; i < 4; ++i)
#pragma unroll
        for (int j = 0; j < 4; ++j) acc[i][j] += av[i] * bv[j];
    }
    __syncthreads();
  }

  int gn = n0 + tx * 4;
  if (gn < N) {
    float4 bv = *(const float4*)(bias + gn);
#pragma unroll
    for (int i = 0; i < 4; ++i) {
      int gm = m0 + ty * 4 + i;
      if (gm >= M) continue;
      float4 cv;
      cv.x = acc[i][0] + bv.x;
      cv.y = acc[i][1] + bv.y;
      cv.z = acc[i][2] + bv.z;
      cv.w = acc[i][3] + bv.w;
      if (RELU) {
        cv.x = fmaxf(cv.x, 0.f); cv.y = fmaxf(cv.y, 0.f);
        cv.z = fmaxf(cv.z, 0.f); cv.w = fmaxf(cv.w, 0.f);
      }
      *(float4*)(C + (size_t)gm * N + gn) = cv;
    }
  }
}

// ---------------- skinny GEMM for M == 8 (decoder rows) --------------------
template <bool RELU>
__global__ __launch_bounds__(256) void skinny_gemm(
    const float* __restrict__ A, const float* __restrict__ W,
    const float* __restrict__ bias, float* __restrict__ C, int N, int K) {
  extern __shared__ float As[];  // 8*K
  int tid = threadIdx.x;
  for (int i = tid; i < 8 * K; i += 256) As[i] = A[i];
  __syncthreads();
  int n = blockIdx.x * 64 + (tid & 63);
  int r0 = tid >> 6;  // rows r0, r0+4
  if (n >= N) return;
  float acc0 = 0.f, acc1 = 0.f;
  const float* a0 = As + r0 * K;
  const float* a1 = As + (r0 + 4) * K;
  for (int k = 0; k < K; ++k) {
    float w = W[(size_t)k * N + n];
    acc0 += a0[k] * w;
    acc1 += a1[k] * w;
  }
  float b = bias[n];
  float v0 = acc0 + b, v1 = acc1 + b;
  if (RELU) { v0 = fmaxf(v0, 0.f); v1 = fmaxf(v1, 0.f); }
  C[(size_t)r0 * N + n] = v0;
  C[(size_t)(r0 + 4) * N + n] = v1;
}

// ---------------- fused attention (SK = 512 fixed) -------------------------
// Q[B,SQ,DM], K/V[B,SEQ,DM]; per-block: one (b,h), 8 query rows.
#define QR 8
__global__ __launch_bounds__(256) void attn_kernel(
    const float* __restrict__ Q, const float* __restrict__ K,
    const float* __restrict__ V, float* __restrict__ O, int SQ) {
  __shared__ float Qs[QR][DK];
  __shared__ float Sc[QR][SEQ];
  __shared__ float Ts[64][DK + 1];

  int tid = threadIdx.x;
  int bh = blockIdx.y;
  int b = bh >> 3, h = bh & 7;
  int q0 = blockIdx.x * QR;
  const size_t baseQ = (size_t)b * SQ * DM + h * DK;
  const size_t baseKV = (size_t)b * SEQ * DM + h * DK;

  for (int i = tid; i < QR * DK; i += 256) {
    int r = i >> 6, d = i & 63;
    Qs[r][d] = (q0 + r < SQ) ? Q[baseQ + (size_t)(q0 + r) * DM + d] : 0.f;
  }
  __syncthreads();

  // scores
  int sr = tid >> 6, sk = tid & 63;
  for (int kt = 0; kt < 8; ++kt) {
    for (int i = tid; i < 64 * DK; i += 256) {
      int kk = i >> 6, d = i & 63;
      Ts[kk][d] = K[baseKV + (size_t)(kt * 64 + kk) * DM + d];
    }
    __syncthreads();
#pragma unroll
    for (int rr = 0; rr < 2; ++rr) {
      int r = sr + rr * 4;
      float s = 0.f;
#pragma unroll
      for (int d = 0; d < DK; ++d) s += Qs[r][d] * Ts[sk][d];
      Sc[r][kt * 64 + sk] = s * 0.125f;
    }
    __syncthreads();
  }

  // softmax (wave wv handles rows wv and wv+4)
  int wv = tid >> 6, lane = tid & 63;
#pragma unroll
  for (int rr = 0; rr < 2; ++rr) {
    int r = wv + rr * 4;
    float mx = -1e30f;
    for (int j = lane; j < SEQ; j += 64) mx = fmaxf(mx, Sc[r][j]);
    for (int o = 32; o > 0; o >>= 1) mx = fmaxf(mx, __shfl_xor(mx, o));
    float sum = 0.f;
    for (int j = lane; j < SEQ; j += 64) {
      float p = __expf(Sc[r][j] - mx);
      Sc[r][j] = p;
      sum += p;
    }
    for (int o = 32; o > 0; o >>= 1) sum += __shfl_xor(sum, o);
    float inv = 1.f / sum;
    for (int j = lane; j < SEQ; j += 64) Sc[r][j] *= inv;
  }
  __syncthreads();

  // O = P @ V
  int od = tid & 63, orr = tid >> 6;
  float o0 = 0.f, o1 = 0.f;
  for (int kt = 0; kt < 8; ++kt) {
    for (int i = tid; i < 64 * DK; i += 256) {
      int kk = i >> 6, d = i & 63;
      Ts[kk][d] = V[baseKV + (size_t)(kt * 64 + kk) * DM + d];
    }
    __syncthreads();
#pragma unroll
    for (int kk = 0; kk < 64; ++kk) {
      float vv = Ts[kk][od];
      o0 += Sc[orr][kt * 64 + kk] * vv;
      o1 += Sc[orr + 4][kt * 64 + kk] * vv;
    }
    __syncthreads();
  }
  if (q0 + orr < SQ) O[baseQ + (size_t)(q0 + orr) * DM + od] = o0;
  if (q0 + orr + 4 < SQ) O[baseQ + (size_t)(q0 + orr + 4) * DM + od] = o1;
}

// ---------------- residual + layernorm -------------------------------------
__global__ __launch_bounds__(256) void add_ln(
    const float* __restrict__ x, const float* __restrict__ res,
    const float* __restrict__ g, const float* __restrict__ beta,
    float* __restrict__ y) {
  int row = blockIdx.x;
  int tid = threadIdx.x;
  const float* xr = x + (size_t)row * DM;
  const float* rr = res + (size_t)row * DM;
  float v0 = xr[tid] + rr[tid];
  float v1 = xr[tid + 256] + rr[tid + 256];
  float s = v0 + v1, sq = v0 * v0 + v1 * v1;
  for (int o = 32; o > 0; o >>= 1) {
    s += __shfl_xor(s, o);
    sq += __shfl_xor(sq, o);
  }
  __shared__ float ps[4], pq[4];
  int wv = tid >> 6;
  if ((tid & 63) == 0) { ps[wv] = s; pq[wv] = sq; }
  __syncthreads();
  s = ps[0] + ps[1] + ps[2] + ps[3];
  sq = pq[0] + pq[1] + pq[2] + pq[3];
  float mean = s * (1.f / DM);
  float var = sq * (1.f / DM) - mean * mean;
  float rstd = rsqrtf(var + 1e-5f);
  y[(size_t)row * DM + tid] = (v0 - mean) * rstd * g[tid] + beta[tid];
  y[(size_t)row * DM + tid + 256] = (v1 - mean) * rstd * g[tid + 256] + beta[tid + 256];
}

// ---------------------------------------------------------------------------
extern "C" void kernel_launch(void* const* d_in, const int* in_sizes, int n_in,
                              void* d_out, int out_size, void* d_ws, size_t ws_size,
                              hipStream_t stream) {
  const int* x = (const int*)d_in[0];
  const int* target = (const int*)d_in[1];
  const float* in_emb = (const float*)d_in[2];
  const float* out_emb = (const float*)d_in[3];
  const float* enc_qkv_w = (const float*)d_in[4];
  const float* enc_qkv_b = (const float*)d_in[5];
  const float* enc_ln1_g = (const float*)d_in[6];
  const float* enc_ln1_b = (const float*)d_in[7];
  const float* enc_ffn1_w = (const float*)d_in[8];
  const float* enc_ffn1_b = (const float*)d_in[9];
  const float* enc_ffn2_w = (const float*)d_in[10];
  const float* enc_ffn2_b = (const float*)d_in[11];
  const float* enc_ln2_g = (const float*)d_in[12];
  const float* enc_ln2_b = (const float*)d_in[13];
  const float* dec_qkv1_w = (const float*)d_in[14];
  const float* dec_qkv1_b = (const float*)d_in[15];
  const float* dec_ln1_g = (const float*)d_in[16];
  const float* dec_ln1_b = (const float*)d_in[17];
  const float* dec_qkv2_w = (const float*)d_in[18];
  const float* dec_qkv2_b = (const float*)d_in[19];
  const float* dec_ln2_g = (const float*)d_in[20];
  const float* dec_ln2_b = (const float*)d_in[21];
  const float* dec_ffn1_w = (const float*)d_in[22];
  const float* dec_ffn1_b = (const float*)d_in[23];
  const float* dec_ffn2_w = (const float*)d_in[24];
  const float* dec_ffn2_b = (const float*)d_in[25];
  const float* dec_ln3_g = (const float*)d_in[26];
  const float* dec_ln3_b = (const float*)d_in[27];
  const float* out_w = (const float*)d_in[28];
  const float* out_b = (const float*)d_in[29];

  const long ACT = (long)NB * SEQ * DM;  // 2M floats
  float* ws = (float*)d_ws;
  float* e = ws;
  float* qb = e + ACT;
  float* kb = qb + ACT;
  float* vb = kb + ACT;
  float* tb = vb + ACT;
  float* hb = tb + ACT;                  // NB*SEQ*DFF = 8M floats
  float* dd = hb + (long)NB * SEQ * DFF;
  float* dq = dd + NB * DM;
  float* da = dq + NB * DM;
  float* dh = da + NB * DM;
  float* df = dh + NB * DFF;

  const int M = NB * SEQ;  // 4096

  // ---- encoder ----
  embed_enc<<<(M * DM) / 256, 256, 0, stream>>>(x, in_emb, e);
  for (int i = 0; i < NL; ++i) {
    // qkv (z-batched over 3)
    gemm_bias<false><<<dim3(DM / GBN, M / GBM, 3), 256, 0, stream>>>(
        e, enc_qkv_w + (size_t)i * 3 * DM * DM, enc_qkv_b + (size_t)i * 3 * DM,
        qb, M, DM, DM, (long)DM * DM, DM, ACT);
    attn_kernel<<<dim3(SEQ / QR, NB * NH), 256, 0, stream>>>(qb, kb, vb, tb, SEQ);
    add_ln<<<M, 256, 0, stream>>>(tb, e, enc_ln1_g + i * DM, enc_ln1_b + i * DM, e);
    gemm_bias<true><<<dim3(DFF / GBN, M / GBM, 1), 256, 0, stream>>>(
        e, enc_ffn1_w + (size_t)i * DM * DFF, enc_ffn1_b + (size_t)i * DFF,
        hb, M, DFF, DM, 0, 0, 0);
    gemm_bias<false><<<dim3(DM / GBN, M / GBM, 1), 256, 0, stream>>>(
        hb, enc_ffn2_w + (size_t)i * DFF * DM, enc_ffn2_b + (size_t)i * DM,
        tb, M, DM, DFF, 0, 0, 0);
    add_ln<<<M, 256, 0, stream>>>(tb, e, enc_ln2_g + i * DM, enc_ln2_b + i * DM, e);
  }

  // ---- decoder (seq len 1) ----
  embed_dec<<<(NB * DM) / 256, 256, 0, stream>>>(target, out_emb, dd);
  for (int i = 0; i < NL; ++i) {
    // self-attention: softmax over 1 element == 1 -> output is V. Only V gemm.
    skinny_gemm<false><<<dim3(DM / 64), 256, 8 * DM * 4, stream>>>(
        dd, dec_qkv1_w + ((size_t)i * 3 + 2) * DM * DM,
        dec_qkv1_b + ((size_t)i * 3 + 2) * DM, dq, DM, DM);
    add_ln<<<NB, 256, 0, stream>>>(dq, dd, dec_ln1_g + i * DM, dec_ln1_b + i * DM, dd);
    // cross attention
    skinny_gemm<false><<<dim3(DM / 64), 256, 8 * DM * 4, stream>>>(
        dd, dec_qkv2_w + ((size_t)i * 3 + 0) * DM * DM,
        dec_qkv2_b + ((size_t)i * 3 + 0) * DM, dq, DM, DM);
    gemm_bias<false><<<dim3(DM / GBN, M / GBM, 2), 256, 0, stream>>>(
        e, dec_qkv2_w + ((size_t)i * 3 + 1) * DM * DM,
        dec_qkv2_b + ((size_t)i * 3 + 1) * DM, kb, M, DM, DM,
        (long)DM * DM, DM, ACT);
    attn_kernel<<<dim3(1, NB * NH), 256, 0, stream>>>(dq, kb, vb, da, 1);
    add_ln<<<NB, 256, 0, stream>>>(da, dd, dec_ln2_g + i * DM, dec_ln2_b + i * DM, dd);
    // ffn
    skinny_gemm<true><<<dim3(DFF / 64), 256, 8 * DM * 4, stream>>>(
        dd, dec_ffn1_w + (size_t)i * DM * DFF, dec_ffn1_b + (size_t)i * DFF, dh, DFF, DM);
    skinny_gemm<false><<<dim3(DM / 64), 256, 8 * DFF * 4, stream>>>(
        dh, dec_ffn2_w + (size_t)i * DFF * DM, dec_ffn2_b + (size_t)i * DM, df, DM, DFF);
    add_ln<<<NB, 256, 0, stream>>>(df, dd, dec_ln3_g + i * DM, dec_ln3_b + i * DM, dd);
  }

  // ---- output projection ----
  skinny_gemm<false><<<dim3((OUTD + 63) / 64), 256, 8 * DM * 4, stream>>>(
      dd, out_w, out_b, (float*)d_out, OUTD, DM);
}

// Round 2
// 3871.207 us; speedup vs baseline: 2.1950x; 2.1950x over previous
//
#include <hip/hip_runtime.h>
#include <hip/hip_bf16.h>

#define DM 512
#define NH 8
#define DK 64
#define SEQ 512
#define NB 8
#define NL 6
#define DFF 2048
#define OUTD 1000
#define EMB_SCALE 22.627416997969522f
#define PE_C (-0.017988946039015984)   // -ln(10000)/512

typedef __bf16 bf16x8 __attribute__((ext_vector_type(8)));
typedef __bf16 bf16x4 __attribute__((ext_vector_type(4)));
typedef float f32x4 __attribute__((ext_vector_type(4)));

// ---------------- PE table ----------------
__global__ __launch_bounds__(256) void pe_kernel(float* __restrict__ pe) {
  int s = blockIdx.x;
  int d2 = threadIdx.x;                  // 0..255 -> dims 2*d2, 2*d2+1
  double div = exp((double)(2 * d2) * PE_C);
  double arg = (double)s * div;
  pe[(size_t)s * DM + 2 * d2] = (float)sin(arg);
  pe[(size_t)s * DM + 2 * d2 + 1] = (float)cos(arg);
}

// ---------------- embedding ----------------
__global__ __launch_bounds__(256) void embed_enc(const int* __restrict__ x,
                                                 const float* __restrict__ emb,
                                                 const float* __restrict__ pe,
                                                 float* __restrict__ e,
                                                 __bf16* __restrict__ eb) {
  int idx = blockIdx.x * 256 + threadIdx.x;   // NB*SEQ*DM
  int d = idx & (DM - 1);
  int bs = idx >> 9;
  int s = bs & (SEQ - 1);
  int tok = x[bs];
  float v = emb[(size_t)tok * DM + d] * EMB_SCALE + pe[(size_t)s * DM + d];
  e[idx] = v;
  eb[idx] = (__bf16)v;
}

__global__ __launch_bounds__(256) void embed_dec(const int* __restrict__ t,
                                                 const float* __restrict__ emb,
                                                 float* __restrict__ dd) {
  int idx = blockIdx.x * 256 + threadIdx.x;   // NB*DM
  int d = idx & (DM - 1);
  int b = idx >> 9;
  float pe = (d & 1) ? 1.0f : 0.0f;
  dd[idx] = emb[(size_t)t[b] * DM + d] * EMB_SCALE + pe;
}

// ---------------- weight transpose fp32[K][N] -> bf16[N][K] ----------------
__global__ __launch_bounds__(256) void transpose_w(const float* __restrict__ W,
                                                   __bf16* __restrict__ WT,
                                                   int K, int N) {
  __shared__ float t[32][33];
  size_t off = (size_t)blockIdx.z * K * N;
  W += off; WT += off;
  int k0 = blockIdx.y * 32, n0 = blockIdx.x * 32;
  int tx = threadIdx.x & 7, ty = threadIdx.x >> 3;  // 8 x 32
  float4 v = *(const float4*)&W[(size_t)(k0 + ty) * N + n0 + tx * 4];
  t[ty][tx * 4 + 0] = v.x; t[ty][tx * 4 + 1] = v.y;
  t[ty][tx * 4 + 2] = v.z; t[ty][tx * 4 + 3] = v.w;
  __syncthreads();
  bf16x4 o;
  o[0] = (__bf16)t[tx * 4 + 0][ty];
  o[1] = (__bf16)t[tx * 4 + 1][ty];
  o[2] = (__bf16)t[tx * 4 + 2][ty];
  o[3] = (__bf16)t[tx * 4 + 3][ty];
  *(bf16x4*)&WT[(size_t)(n0 + ty) * K + k0 + tx * 4] = o;
}

// ---------------- MFMA GEMM: C = A @ W + bias ----------------
// A bf16 [M][K], BT bf16 [N][K]; 128x128 tile, BK=64, 256 threads.
#define LDSP 72
template <bool RELU, bool WF32, bool WBF16>
__global__ __launch_bounds__(256) void mfma_gemm(
    const __bf16* __restrict__ A, const __bf16* __restrict__ BT,
    const float* __restrict__ bias, float* __restrict__ C,
    __bf16* __restrict__ Cb, int M, int N, int K,
    long btStride, long bStride, long cStride) {
  int z = blockIdx.z;
  BT += (size_t)z * btStride;
  bias += (size_t)z * bStride;
  if (WF32) C += (size_t)z * cStride;
  if (WBF16) Cb += (size_t)z * cStride;

  __shared__ __bf16 As[128 * LDSP];
  __shared__ __bf16 Bs[128 * LDSP];

  int tid = threadIdx.x;
  int wave = tid >> 6, lane = tid & 63;
  int wm = wave >> 1, wn = wave & 1;
  int quad = lane >> 4, l16 = lane & 15;
  int m0 = blockIdx.y * 128, n0 = blockIdx.x * 128;

  f32x4 acc[4][4];
#pragma unroll
  for (int i = 0; i < 4; ++i)
#pragma unroll
    for (int j = 0; j < 4; ++j) acc[i][j] = (f32x4){0.f, 0.f, 0.f, 0.f};

  for (int k0 = 0; k0 < K; k0 += 64) {
#pragma unroll
    for (int j = 0; j < 4; ++j) {
      int c = j * 256 + tid;
      int row = c >> 3, col = (c & 7) * 8;
      *(bf16x8*)&As[row * LDSP + col] =
          *(const bf16x8*)&A[(size_t)(m0 + row) * K + k0 + col];
      *(bf16x8*)&Bs[row * LDSP + col] =
          *(const bf16x8*)&BT[(size_t)(n0 + row) * K + k0 + col];
    }
    __syncthreads();
#pragma unroll
    for (int kk = 0; kk < 64; kk += 32) {
      bf16x8 af[4], bf[4];
#pragma unroll
      for (int i = 0; i < 4; ++i) {
        af[i] = *(const bf16x8*)&As[(wm * 64 + i * 16 + l16) * LDSP + kk + quad * 8];
        bf[i] = *(const bf16x8*)&Bs[(wn * 64 + i * 16 + l16) * LDSP + kk + quad * 8];
      }
#pragma unroll
      for (int mi = 0; mi < 4; ++mi)
#pragma unroll
        for (int ni = 0; ni < 4; ++ni)
          acc[mi][ni] = __builtin_amdgcn_mfma_f32_16x16x32_bf16(
              af[mi], bf[ni], acc[mi][ni], 0, 0, 0);
    }
    __syncthreads();
  }

#pragma unroll
  for (int ni = 0; ni < 4; ++ni) {
    int col = n0 + wn * 64 + ni * 16 + l16;
    float bv = bias[col];
#pragma unroll
    for (int mi = 0; mi < 4; ++mi) {
#pragma unroll
      for (int r = 0; r < 4; ++r) {
        int row = m0 + wm * 64 + mi * 16 + quad * 4 + r;
        float v = acc[mi][ni][r] + bv;
        if (RELU) v = fmaxf(v, 0.f);
        if (WF32) C[(size_t)row * N + col] = v;
        if (WBF16) Cb[(size_t)row * N + col] = (__bf16)v;
      }
    }
  }
}

// ---------------- MFMA encoder attention ----------------
// QKV bf16 packed [3][B][S][D]; O fp32 [B][S][D]. Block: (q-tile of 16, bh).
#define SCP 520
__global__ __launch_bounds__(256) void attn_mfma(const __bf16* __restrict__ QKV,
                                                 float* __restrict__ O) {
  __shared__ __bf16 Sc[16 * SCP];   // scores/probs, bf16
  __shared__ __bf16 Tt[64 * LDSP];  // staged K tile (phase1) / V^T tile (phase2)

  const long ACTL = (long)NB * SEQ * DM;
  int tid = threadIdx.x;
  int wave = tid >> 6, lane = tid & 63;
  int quad = lane >> 4, l16 = lane & 15;
  int q0 = blockIdx.x * 16;
  int bh = blockIdx.y, b = bh >> 3, h = bh & 7;
  const __bf16* Q = QKV;
  const __bf16* K = QKV + ACTL;
  const __bf16* V = QKV + 2 * ACTL;
  size_t baseQ = ((size_t)b * SEQ + q0) * DM + h * DK;
  size_t baseKV = ((size_t)b * SEQ) * DM + h * DK;

  // A-fragments of Q for this block's 16 rows (lane l16 = q row)
  bf16x8 af0 = *(const bf16x8*)&Q[baseQ + (size_t)l16 * DM + quad * 8];
  bf16x8 af1 = *(const bf16x8*)&Q[baseQ + (size_t)l16 * DM + 32 + quad * 8];

  // ---- phase 1: S = Q K^T / 8 ----
  for (int kt = 0; kt < 8; ++kt) {
    __syncthreads();
    for (int i = tid; i < 512; i += 256) {  // 64 keys x 8 chunks
      int key = i >> 3, d8 = (i & 7) * 8;
      *(bf16x8*)&Tt[key * LDSP + d8] =
          *(const bf16x8*)&K[baseKV + (size_t)(kt * 64 + key) * DM + d8];
    }
    __syncthreads();
    f32x4 acc = (f32x4){0.f, 0.f, 0.f, 0.f};
    int krow = wave * 16 + l16;  // key within tile
    bf16x8 b0 = *(const bf16x8*)&Tt[krow * LDSP + quad * 8];
    bf16x8 b1 = *(const bf16x8*)&Tt[krow * LDSP + 32 + quad * 8];
    acc = __builtin_amdgcn_mfma_f32_16x16x32_bf16(af0, b0, acc, 0, 0, 0);
    acc = __builtin_amdgcn_mfma_f32_16x16x32_bf16(af1, b1, acc, 0, 0, 0);
#pragma unroll
    for (int r = 0; r < 4; ++r)
      Sc[(quad * 4 + r) * SCP + kt * 64 + wave * 16 + l16] =
          (__bf16)(acc[r] * 0.125f);
  }
  __syncthreads();

  // ---- softmax (wave handles 4 rows) ----
#pragma unroll
  for (int rr = 0; rr < 4; ++rr) {
    int r = wave * 4 + rr;
    float v[8];
    float mx = -1e30f;
#pragma unroll
    for (int j = 0; j < 8; ++j) {
      v[j] = (float)Sc[r * SCP + j * 64 + lane];
      mx = fmaxf(mx, v[j]);
    }
    for (int o = 32; o > 0; o >>= 1) mx = fmaxf(mx, __shfl_xor(mx, o));
    float sum = 0.f;
#pragma unroll
    for (int j = 0; j < 8; ++j) { v[j] = __expf(v[j] - mx); sum += v[j]; }
    for (int o = 32; o > 0; o >>= 1) sum += __shfl_xor(sum, o);
    float inv = 1.f / sum;
#pragma unroll
    for (int j = 0; j < 8; ++j)
      Sc[r * SCP + j * 64 + lane] = (__bf16)(v[j] * inv);
  }

  // ---- phase 2: O = P V ; wave w owns d-slice [w*16, w*16+16) ----
  f32x4 oacc = (f32x4){0.f, 0.f, 0.f, 0.f};
  for (int kt = 0; kt < 8; ++kt) {
    __syncthreads();
    for (int i = tid; i < 512; i += 256) {  // transpose V tile: Tt[d][key]
      int key = i >> 3, d8 = (i & 7) * 8;
      bf16x8 vv = *(const bf16x8*)&V[baseKV + (size_t)(kt * 64 + key) * DM + d8];
#pragma unroll
      for (int jj = 0; jj < 8; ++jj) Tt[(d8 + jj) * LDSP + key] = vv[jj];
    }
    __syncthreads();
#pragma unroll
    for (int kk = 0; kk < 64; kk += 32) {
      bf16x8 pa = *(const bf16x8*)&Sc[l16 * SCP + kt * 64 + kk + quad * 8];
      bf16x8 vb = *(const bf16x8*)&Tt[(wave * 16 + l16) * LDSP + kk + quad * 8];
      oacc = __builtin_amdgcn_mfma_f32_16x16x32_bf16(pa, vb, oacc, 0, 0, 0);
    }
  }
#pragma unroll
  for (int r = 0; r < 4; ++r)
    O[((size_t)b * SEQ + q0 + quad * 4 + r) * DM + h * DK + wave * 16 + l16] =
        oacc[r];
}

// ---------------- skinny GEMM (decoder, M == 8, fp32) ----------------
template <bool RELU>
__global__ __launch_bounds__(256) void skinny_gemm(
    const float* __restrict__ A, const float* __restrict__ W,
    const float* __restrict__ bias, float* __restrict__ C, int N, int K) {
  extern __shared__ float Ass[];
  int tid = threadIdx.x;
  for (int i = tid; i < 8 * K; i += 256) Ass[i] = A[i];
  __syncthreads();
  int n = blockIdx.x * 64 + (tid & 63);
  int r0 = tid >> 6;
  if (n >= N) return;
  float acc0 = 0.f, acc1 = 0.f;
  const float* a0 = Ass + r0 * K;
  const float* a1 = Ass + (r0 + 4) * K;
  for (int k = 0; k < K; ++k) {
    float w = W[(size_t)k * N + n];
    acc0 += a0[k] * w;
    acc1 += a1[k] * w;
  }
  float b = bias[n];
  float v0 = acc0 + b, v1 = acc1 + b;
  if (RELU) { v0 = fmaxf(v0, 0.f); v1 = fmaxf(v1, 0.f); }
  C[(size_t)r0 * N + n] = v0;
  C[(size_t)(r0 + 4) * N + n] = v1;
}

// ---------------- fp32 attention (decoder only, SQ=1) ----------------
#define QR 8
__global__ __launch_bounds__(256) void attn_kernel(
    const float* __restrict__ Q, const float* __restrict__ K,
    const float* __restrict__ V, float* __restrict__ O, int SQ) {
  __shared__ float Qs[QR][DK];
  __shared__ float Sc2[QR][SEQ];
  __shared__ float Ts[64][DK + 1];

  int tid = threadIdx.x;
  int bh = blockIdx.y;
  int b = bh >> 3, h = bh & 7;
  int q0 = blockIdx.x * QR;
  const size_t baseQ = (size_t)b * SQ * DM + h * DK;
  const size_t baseKV = (size_t)b * SEQ * DM + h * DK;

  for (int i = tid; i < QR * DK; i += 256) {
    int r = i >> 6, d = i & 63;
    Qs[r][d] = (q0 + r < SQ) ? Q[baseQ + (size_t)(q0 + r) * DM + d] : 0.f;
  }
  __syncthreads();

  int sr = tid >> 6, sk = tid & 63;
  for (int kt = 0; kt < 8; ++kt) {
    for (int i = tid; i < 64 * DK; i += 256) {
      int kk = i >> 6, d = i & 63;
      Ts[kk][d] = K[baseKV + (size_t)(kt * 64 + kk) * DM + d];
    }
    __syncthreads();
#pragma unroll
    for (int rr = 0; rr < 2; ++rr) {
      int r = sr + rr * 4;
      float s = 0.f;
#pragma unroll
      for (int d = 0; d < DK; ++d) s += Qs[r][d] * Ts[sk][d];
      Sc2[r][kt * 64 + sk] = s * 0.125f;
    }
    __syncthreads();
  }

  int wv = tid >> 6, lane = tid & 63;
#pragma unroll
  for (int rr = 0; rr < 2; ++rr) {
    int r = wv + rr * 4;
    float mx = -1e30f;
    for (int j = lane; j < SEQ; j += 64) mx = fmaxf(mx, Sc2[r][j]);
    for (int o = 32; o > 0; o >>= 1) mx = fmaxf(mx, __shfl_xor(mx, o));
    float sum = 0.f;
    for (int j = lane; j < SEQ; j += 64) {
      float p = __expf(Sc2[r][j] - mx);
      Sc2[r][j] = p;
      sum += p;
    }
    for (int o = 32; o > 0; o >>= 1) sum += __shfl_xor(sum, o);
    float inv = 1.f / sum;
    for (int j = lane; j < SEQ; j += 64) Sc2[r][j] *= inv;
  }
  __syncthreads();

  int od = tid & 63, orr = tid >> 6;
  float o0 = 0.f, o1 = 0.f;
  for (int kt = 0; kt < 8; ++kt) {
    for (int i = tid; i < 64 * DK; i += 256) {
      int kk = i >> 6, d = i & 63;
      Ts[kk][d] = V[baseKV + (size_t)(kt * 64 + kk) * DM + d];
    }
    __syncthreads();
#pragma unroll
    for (int kk = 0; kk < 64; ++kk) {
      float vv = Ts[kk][od];
      o0 += Sc2[orr][kt * 64 + kk] * vv;
      o1 += Sc2[orr + 4][kt * 64 + kk] * vv;
    }
    __syncthreads();
  }
  if (q0 + orr < SQ) O[baseQ + (size_t)(q0 + orr) * DM + od] = o0;
  if (q0 + orr + 4 < SQ) O[baseQ + (size_t)(q0 + orr + 4) * DM + od] = o1;
}

// ---------------- residual + layernorm ----------------
template <bool WB>
__global__ __launch_bounds__(256) void add_ln(
    const float* __restrict__ x, const float* __restrict__ res,
    const float* __restrict__ g, const float* __restrict__ beta,
    float* __restrict__ y, __bf16* __restrict__ yb) {
  int row = blockIdx.x;
  int tid = threadIdx.x;
  const float* xr = x + (size_t)row * DM;
  const float* rr = res + (size_t)row * DM;
  float v0 = xr[tid] + rr[tid];
  float v1 = xr[tid + 256] + rr[tid + 256];
  float s = v0 + v1, sq = v0 * v0 + v1 * v1;
  for (int o = 32; o > 0; o >>= 1) {
    s += __shfl_xor(s, o);
    sq += __shfl_xor(sq, o);
  }
  __shared__ float ps[4], pq[4];
  int wv = tid >> 6;
  if ((tid & 63) == 0) { ps[wv] = s; pq[wv] = sq; }
  __syncthreads();
  s = ps[0] + ps[1] + ps[2] + ps[3];
  sq = pq[0] + pq[1] + pq[2] + pq[3];
  float mean = s * (1.f / DM);
  float var = sq * (1.f / DM) - mean * mean;
  float rstd = rsqrtf(var + 1e-5f);
  float o0 = (v0 - mean) * rstd * g[tid] + beta[tid];
  float o1 = (v1 - mean) * rstd * g[tid + 256] + beta[tid + 256];
  y[(size_t)row * DM + tid] = o0;
  y[(size_t)row * DM + tid + 256] = o1;
  if (WB) {
    yb[(size_t)row * DM + tid] = (__bf16)o0;
    yb[(size_t)row * DM + tid + 256] = (__bf16)o1;
  }
}

// ---------------------------------------------------------------------------
extern "C" void kernel_launch(void* const* d_in, const int* in_sizes, int n_in,
                              void* d_out, int out_size, void* d_ws, size_t ws_size,
                              hipStream_t stream) {
  const int* x = (const int*)d_in[0];
  const int* target = (const int*)d_in[1];
  const float* in_emb = (const float*)d_in[2];
  const float* out_emb = (const float*)d_in[3];
  const float* enc_qkv_w = (const float*)d_in[4];
  const float* enc_qkv_b = (const float*)d_in[5];
  const float* enc_ln1_g = (const float*)d_in[6];
  const float* enc_ln1_b = (const float*)d_in[7];
  const float* enc_ffn1_w = (const float*)d_in[8];
  const float* enc_ffn1_b = (const float*)d_in[9];
  const float* enc_ffn2_w = (const float*)d_in[10];
  const float* enc_ffn2_b = (const float*)d_in[11];
  const float* enc_ln2_g = (const float*)d_in[12];
  const float* enc_ln2_b = (const float*)d_in[13];
  const float* dec_qkv1_w = (const float*)d_in[14];
  const float* dec_qkv1_b = (const float*)d_in[15];
  const float* dec_ln1_g = (const float*)d_in[16];
  const float* dec_ln1_b = (const float*)d_in[17];
  const float* dec_qkv2_w = (const float*)d_in[18];
  const float* dec_qkv2_b = (const float*)d_in[19];
  const float* dec_ln2_g = (const float*)d_in[20];
  const float* dec_ln2_b = (const float*)d_in[21];
  const float* dec_ffn1_w = (const float*)d_in[22];
  const float* dec_ffn1_b = (const float*)d_in[23];
  const float* dec_ffn2_w = (const float*)d_in[24];
  const float* dec_ffn2_b = (const float*)d_in[25];
  const float* dec_ln3_g = (const float*)d_in[26];
  const float* dec_ln3_b = (const float*)d_in[27];
  const float* out_w = (const float*)d_in[28];
  const float* out_b = (const float*)d_in[29];

  const long ACTL = (long)NB * SEQ * DM;           // 2M elems
  const int M = NB * SEQ;                           // 4096

  char* p = (char*)d_ws;
  float* e = (float*)p;            p += ACTL * 4;
  float* tb = (float*)p;           p += ACTL * 4;
  float* kvf = (float*)p;          p += 2 * ACTL * 4;   // cross K,V fp32
  float* pe = (float*)p;           p += (long)SEQ * DM * 4;
  float* dd = (float*)p;           p += NB * DM * 4;
  float* dq = (float*)p;           p += NB * DM * 4;
  float* da = (float*)p;           p += NB * DM * 4;
  float* dh = (float*)p;           p += NB * DFF * 4;
  float* df = (float*)p;           p += NB * DM * 4;
  p = (char*)(((uintptr_t)p + 255) & ~(uintptr_t)255);
  __bf16* eb = (__bf16*)p;         p += ACTL * 2;
  __bf16* qkvb = (__bf16*)p;       p += 3 * ACTL * 2;   // q,k,v bf16
  __bf16* hbb = (__bf16*)p;        p += (long)M * DFF * 2;
  __bf16* wtq = (__bf16*)p;        p += 18L * DM * DM * 2;
  __bf16* wtf1 = (__bf16*)p;       p += 6L * DM * DFF * 2;
  __bf16* wtf2 = (__bf16*)p;       p += 6L * DFF * DM * 2;
  __bf16* wtd = (__bf16*)p;        p += 18L * DM * DM * 2;

  const long WQS = (long)DM * DM;     // 262144
  const long WFS = (long)DM * DFF;    // 1048576

  // ---- one-time (per launch) prep ----
  pe_kernel<<<SEQ, 256, 0, stream>>>(pe);
  transpose_w<<<dim3(16, 16, 18), 256, 0, stream>>>(enc_qkv_w, wtq, DM, DM);
  transpose_w<<<dim3(64, 16, 6), 256, 0, stream>>>(enc_ffn1_w, wtf1, DM, DFF);
  transpose_w<<<dim3(16, 64, 6), 256, 0, stream>>>(enc_ffn2_w, wtf2, DFF, DM);
  transpose_w<<<dim3(16, 16, 18), 256, 0, stream>>>(dec_qkv2_w, wtd, DM, DM);

  // ---- encoder ----
  embed_enc<<<(M * DM) / 256, 256, 0, stream>>>(x, in_emb, pe, e, eb);
  for (int i = 0; i < NL; ++i) {
    mfma_gemm<false, false, true><<<dim3(4, 32, 3), 256, 0, stream>>>(
        eb, wtq + (size_t)i * 3 * WQS, enc_qkv_b + (size_t)i * 3 * DM,
        nullptr, qkvb, M, DM, DM, WQS, DM, ACTL);
    attn_mfma<<<dim3(SEQ / 16, NB * NH), 256, 0, stream>>>(qkvb, tb);
    add_ln<true><<<M, 256, 0, stream>>>(tb, e, enc_ln1_g + i * DM,
                                        enc_ln1_b + i * DM, e, eb);
    mfma_gemm<true, false, true><<<dim3(16, 32, 1), 256, 0, stream>>>(
        eb, wtf1 + (size_t)i * WFS, enc_ffn1_b + (size_t)i * DFF,
        nullptr, hbb, M, DFF, DM, 0, 0, 0);
    mfma_gemm<false, true, false><<<dim3(4, 32, 1), 256, 0, stream>>>(
        hbb, wtf2 + (size_t)i * WFS, enc_ffn2_b + (size_t)i * DM,
        tb, nullptr, M, DM, DFF, 0, 0, 0);
    add_ln<true><<<M, 256, 0, stream>>>(tb, e, enc_ln2_g + i * DM,
                                        enc_ln2_b + i * DM, e, eb);
  }

  // ---- decoder (seq len 1, fp32 path) ----
  embed_dec<<<(NB * DM) / 256, 256, 0, stream>>>(target, out_emb, dd);
  for (int i = 0; i < NL; ++i) {
    // self-attn: softmax over 1 element => output == V
    skinny_gemm<false><<<dim3(DM / 64), 256, 8 * DM * 4, stream>>>(
        dd, dec_qkv1_w + ((size_t)i * 3 + 2) * WQS,
        dec_qkv1_b + ((size_t)i * 3 + 2) * DM, dq, DM, DM);
    add_ln<false><<<NB, 256, 0, stream>>>(dq, dd, dec_ln1_g + i * DM,
                                          dec_ln1_b + i * DM, dd, nullptr);
    // cross attention
    skinny_gemm<false><<<dim3(DM / 64), 256, 8 * DM * 4, stream>>>(
        dd, dec_qkv2_w + ((size_t)i * 3 + 0) * WQS,
        dec_qkv2_b + ((size_t)i * 3 + 0) * DM, dq, DM, DM);
    mfma_gemm<false, true, false><<<dim3(4, 32, 2), 256, 0, stream>>>(
        eb, wtd + ((size_t)i * 3 + 1) * WQS, dec_qkv2_b + ((size_t)i * 3 + 1) * DM,
        kvf, nullptr, M, DM, DM, WQS, DM, ACTL);
    attn_kernel<<<dim3(1, NB * NH), 256, 0, stream>>>(dq, kvf, kvf + ACTL, da, 1);
    add_ln<false><<<NB, 256, 0, stream>>>(da, dd, dec_ln2_g + i * DM,
                                          dec_ln2_b + i * DM, dd, nullptr);
    // ffn
    skinny_gemm<true><<<dim3(DFF / 64), 256, 8 * DM * 4, stream>>>(
        dd, dec_ffn1_w + (size_t)i * WFS, dec_ffn1_b + (size_t)i * DFF, dh, DFF, DM);
    skinny_gemm<false><<<dim3(DM / 64), 256, 8 * DFF * 4, stream>>>(
        dh, dec_ffn2_w + (size_t)i * WFS, dec_ffn2_b + (size_t)i * DM, df, DM, DFF);
    add_ln<false><<<NB, 256, 0, stream>>>(df, dd, dec_ln3_g + i * DM,
                                          dec_ln3_b + i * DM, dd, nullptr);
  }

  skinny_gemm<false><<<dim3((OUTD + 63) / 64), 256, 8 * DM * 4, stream>>>(
      dd, out_w, out_b, (float*)d_out, OUTD, DM);
}

// Round 3
// 1732.390 us; speedup vs baseline: 4.9050x; 2.2346x over previous
//
#include <hip/hip_runtime.h>
#include <hip/hip_bf16.h>

#define DM 512
#define NH 8
#define DK 64
#define SEQ 512
#define NB 8
#define NL 6
#define DFF 2048
#define OUTD 1000
#define EMB_SCALE 22.627416997969522f
#define PE_C (-0.017988946039015984)   // -ln(10000)/512

typedef __bf16 bf16x8 __attribute__((ext_vector_type(8)));
typedef __bf16 bf16x4 __attribute__((ext_vector_type(4)));
typedef float f32x4 __attribute__((ext_vector_type(4)));

// ---------------- PE table ----------------
__global__ __launch_bounds__(256) void pe_kernel(float* __restrict__ pe) {
  int s = blockIdx.x;
  int d2 = threadIdx.x;
  double div = exp((double)(2 * d2) * PE_C);
  double arg = (double)s * div;
  pe[(size_t)s * DM + 2 * d2] = (float)sin(arg);
  pe[(size_t)s * DM + 2 * d2 + 1] = (float)cos(arg);
}

// ---------------- embedding ----------------
__global__ __launch_bounds__(256) void embed_enc(const int* __restrict__ x,
                                                 const float* __restrict__ emb,
                                                 const float* __restrict__ pe,
                                                 float* __restrict__ e,
                                                 __bf16* __restrict__ eb) {
  int idx = blockIdx.x * 256 + threadIdx.x;
  int d = idx & (DM - 1);
  int bs = idx >> 9;
  int s = bs & (SEQ - 1);
  int tok = x[bs];
  float v = emb[(size_t)tok * DM + d] * EMB_SCALE + pe[(size_t)s * DM + d];
  e[idx] = v;
  eb[idx] = (__bf16)v;
}

__global__ __launch_bounds__(256) void embed_dec(const int* __restrict__ t,
                                                 const float* __restrict__ emb,
                                                 float* __restrict__ dd) {
  int idx = blockIdx.x * 256 + threadIdx.x;
  int d = idx & (DM - 1);
  int b = idx >> 9;
  float pe = (d & 1) ? 1.0f : 0.0f;
  dd[idx] = emb[(size_t)t[b] * DM + d] * EMB_SCALE + pe;
}

// ---------------- weight transpose fp32[K][N] -> bf16[N][K] ----------------
__global__ __launch_bounds__(256) void transpose_w(const float* __restrict__ W,
                                                   __bf16* __restrict__ WT,
                                                   int K, int N) {
  __shared__ float t[32][33];
  size_t off = (size_t)blockIdx.z * K * N;
  W += off; WT += off;
  int k0 = blockIdx.y * 32, n0 = blockIdx.x * 32;
  int tx = threadIdx.x & 7, ty = threadIdx.x >> 3;
  float4 v = *(const float4*)&W[(size_t)(k0 + ty) * N + n0 + tx * 4];
  t[ty][tx * 4 + 0] = v.x; t[ty][tx * 4 + 1] = v.y;
  t[ty][tx * 4 + 2] = v.z; t[ty][tx * 4 + 3] = v.w;
  __syncthreads();
  bf16x4 o;
  o[0] = (__bf16)t[tx * 4 + 0][ty];
  o[1] = (__bf16)t[tx * 4 + 1][ty];
  o[2] = (__bf16)t[tx * 4 + 2][ty];
  o[3] = (__bf16)t[tx * 4 + 3][ty];
  *(bf16x4*)&WT[(size_t)(n0 + ty) * K + k0 + tx * 4] = o;
}

// ---------------- MFMA GEMM (encoder) ----------------
#define LDSP 72
template <bool RELU, bool WF32, bool WBF16>
__global__ __launch_bounds__(256) void mfma_gemm(
    const __bf16* __restrict__ A, const __bf16* __restrict__ BT,
    const float* __restrict__ bias, float* __restrict__ C,
    __bf16* __restrict__ Cb, int M, int N, int K,
    long btStride, long bStride, long cStride) {
  int z = blockIdx.z;
  BT += (size_t)z * btStride;
  bias += (size_t)z * bStride;
  if (WF32) C += (size_t)z * cStride;
  if (WBF16) Cb += (size_t)z * cStride;

  __shared__ __bf16 As[128 * LDSP];
  __shared__ __bf16 Bs[128 * LDSP];

  int tid = threadIdx.x;
  int wave = tid >> 6, lane = tid & 63;
  int wm = wave >> 1, wn = wave & 1;
  int quad = lane >> 4, l16 = lane & 15;
  int m0 = blockIdx.y * 128, n0 = blockIdx.x * 128;

  f32x4 acc[4][4];
#pragma unroll
  for (int i = 0; i < 4; ++i)
#pragma unroll
    for (int j = 0; j < 4; ++j) acc[i][j] = (f32x4){0.f, 0.f, 0.f, 0.f};

  for (int k0 = 0; k0 < K; k0 += 64) {
#pragma unroll
    for (int j = 0; j < 4; ++j) {
      int c = j * 256 + tid;
      int row = c >> 3, col = (c & 7) * 8;
      *(bf16x8*)&As[row * LDSP + col] =
          *(const bf16x8*)&A[(size_t)(m0 + row) * K + k0 + col];
      *(bf16x8*)&Bs[row * LDSP + col] =
          *(const bf16x8*)&BT[(size_t)(n0 + row) * K + k0 + col];
    }
    __syncthreads();
#pragma unroll
    for (int kk = 0; kk < 64; kk += 32) {
      bf16x8 af[4], bf[4];
#pragma unroll
      for (int i = 0; i < 4; ++i) {
        af[i] = *(const bf16x8*)&As[(wm * 64 + i * 16 + l16) * LDSP + kk + quad * 8];
        bf[i] = *(const bf16x8*)&Bs[(wn * 64 + i * 16 + l16) * LDSP + kk + quad * 8];
      }
#pragma unroll
      for (int mi = 0; mi < 4; ++mi)
#pragma unroll
        for (int ni = 0; ni < 4; ++ni)
          acc[mi][ni] = __builtin_amdgcn_mfma_f32_16x16x32_bf16(
              af[mi], bf[ni], acc[mi][ni], 0, 0, 0);
    }
    __syncthreads();
  }

#pragma unroll
  for (int ni = 0; ni < 4; ++ni) {
    int col = n0 + wn * 64 + ni * 16 + l16;
    float bv = bias[col];
#pragma unroll
    for (int mi = 0; mi < 4; ++mi) {
#pragma unroll
      for (int r = 0; r < 4; ++r) {
        int row = m0 + wm * 64 + mi * 16 + quad * 4 + r;
        float v = acc[mi][ni][r] + bv;
        if (RELU) v = fmaxf(v, 0.f);
        if (WF32) C[(size_t)row * N + col] = v;
        if (WBF16) Cb[(size_t)row * N + col] = (__bf16)v;
      }
    }
  }
}

// ---------------- MFMA encoder attention ----------------
#define SCP 520
__global__ __launch_bounds__(256) void attn_mfma(const __bf16* __restrict__ QKV,
                                                 float* __restrict__ O) {
  __shared__ __bf16 Sc[16 * SCP];
  __shared__ __bf16 Tt[64 * LDSP];

  const long ACTL = (long)NB * SEQ * DM;
  int tid = threadIdx.x;
  int wave = tid >> 6, lane = tid & 63;
  int quad = lane >> 4, l16 = lane & 15;
  int q0 = blockIdx.x * 16;
  int bh = blockIdx.y, b = bh >> 3, h = bh & 7;
  const __bf16* Q = QKV;
  const __bf16* K = QKV + ACTL;
  const __bf16* V = QKV + 2 * ACTL;
  size_t baseQ = ((size_t)b * SEQ + q0) * DM + h * DK;
  size_t baseKV = ((size_t)b * SEQ) * DM + h * DK;

  bf16x8 af0 = *(const bf16x8*)&Q[baseQ + (size_t)l16 * DM + quad * 8];
  bf16x8 af1 = *(const bf16x8*)&Q[baseQ + (size_t)l16 * DM + 32 + quad * 8];

  for (int kt = 0; kt < 8; ++kt) {
    __syncthreads();
    for (int i = tid; i < 512; i += 256) {
      int key = i >> 3, d8 = (i & 7) * 8;
      *(bf16x8*)&Tt[key * LDSP + d8] =
          *(const bf16x8*)&K[baseKV + (size_t)(kt * 64 + key) * DM + d8];
    }
    __syncthreads();
    f32x4 acc = (f32x4){0.f, 0.f, 0.f, 0.f};
    int krow = wave * 16 + l16;
    bf16x8 b0 = *(const bf16x8*)&Tt[krow * LDSP + quad * 8];
    bf16x8 b1 = *(const bf16x8*)&Tt[krow * LDSP + 32 + quad * 8];
    acc = __builtin_amdgcn_mfma_f32_16x16x32_bf16(af0, b0, acc, 0, 0, 0);
    acc = __builtin_amdgcn_mfma_f32_16x16x32_bf16(af1, b1, acc, 0, 0, 0);
#pragma unroll
    for (int r = 0; r < 4; ++r)
      Sc[(quad * 4 + r) * SCP + kt * 64 + wave * 16 + l16] =
          (__bf16)(acc[r] * 0.125f);
  }
  __syncthreads();

#pragma unroll
  for (int rr = 0; rr < 4; ++rr) {
    int r = wave * 4 + rr;
    float v[8];
    float mx = -1e30f;
#pragma unroll
    for (int j = 0; j < 8; ++j) {
      v[j] = (float)Sc[r * SCP + j * 64 + lane];
      mx = fmaxf(mx, v[j]);
    }
    for (int o = 32; o > 0; o >>= 1) mx = fmaxf(mx, __shfl_xor(mx, o));
    float sum = 0.f;
#pragma unroll
    for (int j = 0; j < 8; ++j) { v[j] = __expf(v[j] - mx); sum += v[j]; }
    for (int o = 32; o > 0; o >>= 1) sum += __shfl_xor(sum, o);
    float inv = 1.f / sum;
#pragma unroll
    for (int j = 0; j < 8; ++j)
      Sc[r * SCP + j * 64 + lane] = (__bf16)(v[j] * inv);
  }

  f32x4 oacc = (f32x4){0.f, 0.f, 0.f, 0.f};
  for (int kt = 0; kt < 8; ++kt) {
    __syncthreads();
    for (int i = tid; i < 512; i += 256) {
      int key = i >> 3, d8 = (i & 7) * 8;
      bf16x8 vv = *(const bf16x8*)&V[baseKV + (size_t)(kt * 64 + key) * DM + d8];
#pragma unroll
      for (int jj = 0; jj < 8; ++jj) Tt[(d8 + jj) * LDSP + key] = vv[jj];
    }
    __syncthreads();
#pragma unroll
    for (int kk = 0; kk < 64; kk += 32) {
      bf16x8 pa = *(const bf16x8*)&Sc[l16 * SCP + kt * 64 + kk + quad * 8];
      bf16x8 vb = *(const bf16x8*)&Tt[(wave * 16 + l16) * LDSP + kk + quad * 8];
      oacc = __builtin_amdgcn_mfma_f32_16x16x32_bf16(pa, vb, oacc, 0, 0, 0);
    }
  }
#pragma unroll
  for (int r = 0; r < 4; ++r)
    O[((size_t)b * SEQ + q0 + quad * 4 + r) * DM + h * DK + wave * 16 + l16] =
        oacc[r];
}

// ---------------- split-K skinny GEMM (decoder, M == 8) ----------------
// C (pre-zeroed) += A[8,Kc-chunk] @ W[Kc-chunk, N]; optional relu(A+abias).
// grid: (ceil(N/64), K/Kc); block 256 = 64 n-cols x 4 k-subs.
template <bool RELUA>
__global__ __launch_bounds__(256) void skinny_splitk(
    const float* __restrict__ A, const float* __restrict__ abias,
    const float* __restrict__ W, float* __restrict__ C,
    int N, int K, int Kc) {
  __shared__ float As[8 * 64];        // Kc <= 64
  __shared__ float red[4][8][64];

  int tid = threadIdx.x;
  int kbase = blockIdx.y * Kc;
  for (int i = tid; i < 8 * Kc; i += 256) {
    int r = i / Kc, k = i - r * Kc;
    float v = A[(size_t)r * K + kbase + k];
    if (RELUA) v = fmaxf(v + abias[kbase + k], 0.f);
    As[r * 64 + k] = v;
  }
  __syncthreads();

  int tn = tid & 63, tk = tid >> 6;
  int n = blockIdx.x * 64 + tn;
  float acc[8] = {};
  if (n < N) {
    for (int k = tk; k < Kc; k += 4) {
      float w = W[(size_t)(kbase + k) * N + n];
#pragma unroll
      for (int r = 0; r < 8; ++r) acc[r] += As[r * 64 + k] * w;
    }
  }
#pragma unroll
  for (int r = 0; r < 8; ++r) red[tk][r][tn] = acc[r];
  __syncthreads();
  if (n < N) {
#pragma unroll
    for (int rr = 0; rr < 2; ++rr) {
      int r = tk * 2 + rr;
      float s = red[0][r][tn] + red[1][r][tn] + red[2][r][tn] + red[3][r][tn];
      atomicAdd(&C[(size_t)r * N + n], s);
    }
  }
}

__global__ __launch_bounds__(256) void add_bias_out(float* __restrict__ out,
                                                    const float* __restrict__ b) {
  int i = blockIdx.x * 256 + threadIdx.x;
  if (i < NB * OUTD) out[i] += b[i % OUTD];
}

// ---------------- fp32 attention (decoder, SQ=1) ----------------
#define QR 8
__global__ __launch_bounds__(256) void attn_kernel(
    const float* __restrict__ Q, const float* __restrict__ qb,
    const float* __restrict__ K, const float* __restrict__ V,
    float* __restrict__ O, int SQ) {
  __shared__ float Qs[QR][DK];
  __shared__ float Sc2[QR][SEQ];
  __shared__ float Ts[64][DK + 1];

  int tid = threadIdx.x;
  int bh = blockIdx.y;
  int b = bh >> 3, h = bh & 7;
  int q0 = blockIdx.x * QR;
  const size_t baseQ = (size_t)b * SQ * DM + h * DK;
  const size_t baseKV = (size_t)b * SEQ * DM + h * DK;

  for (int i = tid; i < QR * DK; i += 256) {
    int r = i >> 6, d = i & 63;
    Qs[r][d] = (q0 + r < SQ) ? Q[baseQ + (size_t)(q0 + r) * DM + d] + qb[h * DK + d]
                             : 0.f;
  }
  __syncthreads();

  int sr = tid >> 6, sk = tid & 63;
  for (int kt = 0; kt < 8; ++kt) {
    for (int i = tid; i < 64 * DK; i += 256) {
      int kk = i >> 6, d = i & 63;
      Ts[kk][d] = K[baseKV + (size_t)(kt * 64 + kk) * DM + d];
    }
    __syncthreads();
#pragma unroll
    for (int rr = 0; rr < 2; ++rr) {
      int r = sr + rr * 4;
      float s = 0.f;
#pragma unroll
      for (int d = 0; d < DK; ++d) s += Qs[r][d] * Ts[sk][d];
      Sc2[r][kt * 64 + sk] = s * 0.125f;
    }
    __syncthreads();
  }

  int wv = tid >> 6, lane = tid & 63;
#pragma unroll
  for (int rr = 0; rr < 2; ++rr) {
    int r = wv + rr * 4;
    float mx = -1e30f;
    for (int j = lane; j < SEQ; j += 64) mx = fmaxf(mx, Sc2[r][j]);
    for (int o = 32; o > 0; o >>= 1) mx = fmaxf(mx, __shfl_xor(mx, o));
    float sum = 0.f;
    for (int j = lane; j < SEQ; j += 64) {
      float p = __expf(Sc2[r][j] - mx);
      Sc2[r][j] = p;
      sum += p;
    }
    for (int o = 32; o > 0; o >>= 1) sum += __shfl_xor(sum, o);
    float inv = 1.f / sum;
    for (int j = lane; j < SEQ; j += 64) Sc2[r][j] *= inv;
  }
  __syncthreads();

  int od = tid & 63, orr = tid >> 6;
  float o0 = 0.f, o1 = 0.f;
  for (int kt = 0; kt < 8; ++kt) {
    for (int i = tid; i < 64 * DK; i += 256) {
      int kk = i >> 6, d = i & 63;
      Ts[kk][d] = V[baseKV + (size_t)(kt * 64 + kk) * DM + d];
    }
    __syncthreads();
#pragma unroll
    for (int kk = 0; kk < 64; ++kk) {
      float vv = Ts[kk][od];
      o0 += Sc2[orr][kt * 64 + kk] * vv;
      o1 += Sc2[orr + 4][kt * 64 + kk] * vv;
    }
    __syncthreads();
  }
  if (q0 + orr < SQ) O[baseQ + (size_t)(q0 + orr) * DM + od] = o0;
  if (q0 + orr + 4 < SQ) O[baseQ + (size_t)(q0 + orr + 4) * DM + od] = o1;
}

// ---------------- residual + layernorm (optional column bias on x) --------
template <bool WB>
__global__ __launch_bounds__(256) void add_ln(
    const float* __restrict__ x, const float* __restrict__ res,
    const float* __restrict__ cbias,
    const float* __restrict__ g, const float* __restrict__ beta,
    float* __restrict__ y, __bf16* __restrict__ yb) {
  int row = blockIdx.x;
  int tid = threadIdx.x;
  const float* xr = x + (size_t)row * DM;
  const float* rr = res + (size_t)row * DM;
  float b0 = cbias ? cbias[tid] : 0.f;
  float b1 = cbias ? cbias[tid + 256] : 0.f;
  float v0 = xr[tid] + b0 + rr[tid];
  float v1 = xr[tid + 256] + b1 + rr[tid + 256];
  float s = v0 + v1, sq = v0 * v0 + v1 * v1;
  for (int o = 32; o > 0; o >>= 1) {
    s += __shfl_xor(s, o);
    sq += __shfl_xor(sq, o);
  }
  __shared__ float ps[4], pq[4];
  int wv = tid >> 6;
  if ((tid & 63) == 0) { ps[wv] = s; pq[wv] = sq; }
  __syncthreads();
  s = ps[0] + ps[1] + ps[2] + ps[3];
  sq = pq[0] + pq[1] + pq[2] + pq[3];
  float mean = s * (1.f / DM);
  float var = sq * (1.f / DM) - mean * mean;
  float rstd = rsqrtf(var + 1e-5f);
  float o0 = (v0 - mean) * rstd * g[tid] + beta[tid];
  float o1 = (v1 - mean) * rstd * g[tid + 256] + beta[tid + 256];
  y[(size_t)row * DM + tid] = o0;
  y[(size_t)row * DM + tid + 256] = o1;
  if (WB) {
    yb[(size_t)row * DM + tid] = (__bf16)o0;
    yb[(size_t)row * DM + tid + 256] = (__bf16)o1;
  }
}

// ---------------------------------------------------------------------------
extern "C" void kernel_launch(void* const* d_in, const int* in_sizes, int n_in,
                              void* d_out, int out_size, void* d_ws, size_t ws_size,
                              hipStream_t stream) {
  const int* x = (const int*)d_in[0];
  const int* target = (const int*)d_in[1];
  const float* in_emb = (const float*)d_in[2];
  const float* out_emb = (const float*)d_in[3];
  const float* enc_qkv_w = (const float*)d_in[4];
  const float* enc_qkv_b = (const float*)d_in[5];
  const float* enc_ln1_g = (const float*)d_in[6];
  const float* enc_ln1_b = (const float*)d_in[7];
  const float* enc_ffn1_w = (const float*)d_in[8];
  const float* enc_ffn1_b = (const float*)d_in[9];
  const float* enc_ffn2_w = (const float*)d_in[10];
  const float* enc_ffn2_b = (const float*)d_in[11];
  const float* enc_ln2_g = (const float*)d_in[12];
  const float* enc_ln2_b = (const float*)d_in[13];
  const float* dec_qkv1_w = (const float*)d_in[14];
  const float* dec_qkv1_b = (const float*)d_in[15];
  const float* dec_ln1_g = (const float*)d_in[16];
  const float* dec_ln1_b = (const float*)d_in[17];
  const float* dec_qkv2_w = (const float*)d_in[18];
  const float* dec_qkv2_b = (const float*)d_in[19];
  const float* dec_ln2_g = (const float*)d_in[20];
  const float* dec_ln2_b = (const float*)d_in[21];
  const float* dec_ffn1_w = (const float*)d_in[22];
  const float* dec_ffn1_b = (const float*)d_in[23];
  const float* dec_ffn2_w = (const float*)d_in[24];
  const float* dec_ffn2_b = (const float*)d_in[25];
  const float* dec_ln3_g = (const float*)d_in[26];
  const float* dec_ln3_b = (const float*)d_in[27];
  const float* out_w = (const float*)d_in[28];
  const float* out_b = (const float*)d_in[29];

  const long ACTL = (long)NB * SEQ * DM;           // 2M elems
  const int M = NB * SEQ;                           // 4096

  char* p = (char*)d_ws;
  float* e = (float*)p;            p += ACTL * 4;
  float* tb = (float*)p;           p += ACTL * 4;
  float* kvf = (float*)p;          p += 2 * ACTL * 4;
  float* pe = (float*)p;           p += (long)SEQ * DM * 4;
  float* dd = (float*)p;           p += NB * DM * 4;
  // decoder scratch (dqv..df must stay contiguous for the single memset)
  float* dqv = (float*)p;          p += NB * DM * 4;
  float* dqq = (float*)p;          p += NB * DM * 4;
  float* dh = (float*)p;           p += NB * DFF * 4;
  float* df = (float*)p;           p += NB * DM * 4;
  float* da = (float*)p;           p += NB * DM * 4;
  p = (char*)(((uintptr_t)p + 255) & ~(uintptr_t)255);
  __bf16* eb = (__bf16*)p;         p += ACTL * 2;
  __bf16* qkvb = (__bf16*)p;       p += 3 * ACTL * 2;
  __bf16* hbb = (__bf16*)p;        p += (long)M * DFF * 2;
  __bf16* wtq = (__bf16*)p;        p += 18L * DM * DM * 2;
  __bf16* wtf1 = (__bf16*)p;       p += 6L * DM * DFF * 2;
  __bf16* wtf2 = (__bf16*)p;       p += 6L * DFF * DM * 2;
  __bf16* wtd = (__bf16*)p;        p += 18L * DM * DM * 2;

  const long WQS = (long)DM * DM;
  const long WFS = (long)DM * DFF;
  const size_t DEC_ZERO_BYTES = (size_t)NB * (DM + DM + DFF + DM) * 4;

  // ---- one-time prep ----
  pe_kernel<<<SEQ, 256, 0, stream>>>(pe);
  transpose_w<<<dim3(16, 16, 18), 256, 0, stream>>>(enc_qkv_w, wtq, DM, DM);
  transpose_w<<<dim3(64, 16, 6), 256, 0, stream>>>(enc_ffn1_w, wtf1, DM, DFF);
  transpose_w<<<dim3(16, 64, 6), 256, 0, stream>>>(enc_ffn2_w, wtf2, DFF, DM);
  transpose_w<<<dim3(16, 16, 18), 256, 0, stream>>>(dec_qkv2_w, wtd, DM, DM);

  // ---- encoder ----
  embed_enc<<<(M * DM) / 256, 256, 0, stream>>>(x, in_emb, pe, e, eb);
  for (int i = 0; i < NL; ++i) {
    mfma_gemm<false, false, true><<<dim3(4, 32, 3), 256, 0, stream>>>(
        eb, wtq + (size_t)i * 3 * WQS, enc_qkv_b + (size_t)i * 3 * DM,
        nullptr, qkvb, M, DM, DM, WQS, DM, ACTL);
    attn_mfma<<<dim3(SEQ / 16, NB * NH), 256, 0, stream>>>(qkvb, tb);
    add_ln<true><<<M, 256, 0, stream>>>(tb, e, nullptr, enc_ln1_g + i * DM,
                                        enc_ln1_b + i * DM, e, eb);
    mfma_gemm<true, false, true><<<dim3(16, 32, 1), 256, 0, stream>>>(
        eb, wtf1 + (size_t)i * WFS, enc_ffn1_b + (size_t)i * DFF,
        nullptr, hbb, M, DFF, DM, 0, 0, 0);
    mfma_gemm<false, true, false><<<dim3(4, 32, 1), 256, 0, stream>>>(
        hbb, wtf2 + (size_t)i * WFS, enc_ffn2_b + (size_t)i * DM,
        tb, nullptr, M, DM, DFF, 0, 0, 0);
    add_ln<true><<<M, 256, 0, stream>>>(tb, e, nullptr, enc_ln2_g + i * DM,
                                        enc_ln2_b + i * DM, e, eb);
  }

  // ---- decoder (seq len 1) ----
  embed_dec<<<(NB * DM) / 256, 256, 0, stream>>>(target, out_emb, dd);
  for (int i = 0; i < NL; ++i) {
    hipMemsetAsync(dqv, 0, DEC_ZERO_BYTES, stream);
    // self-attn (softmax over 1 elem == 1 -> output is V); bias folded in add_ln
    skinny_splitk<false><<<dim3(8, 16), 256, 0, stream>>>(
        dd, nullptr, dec_qkv1_w + ((size_t)i * 3 + 2) * WQS, dqv, DM, DM, 32);
    add_ln<false><<<NB, 256, 0, stream>>>(
        dqv, dd, dec_qkv1_b + ((size_t)i * 3 + 2) * DM,
        dec_ln1_g + i * DM, dec_ln1_b + i * DM, dd, nullptr);
    // cross attention: Q (bias folded into attn), K/V via mfma
    skinny_splitk<false><<<dim3(8, 16), 256, 0, stream>>>(
        dd, nullptr, dec_qkv2_w + ((size_t)i * 3 + 0) * WQS, dqq, DM, DM, 32);
    mfma_gemm<false, true, false><<<dim3(4, 32, 2), 256, 0, stream>>>(
        eb, wtd + ((size_t)i * 3 + 1) * WQS, dec_qkv2_b + ((size_t)i * 3 + 1) * DM,
        kvf, nullptr, M, DM, DM, WQS, DM, ACTL);
    attn_kernel<<<dim3(1, NB * NH), 256, 0, stream>>>(
        dqq, dec_qkv2_b + ((size_t)i * 3 + 0) * DM, kvf, kvf + ACTL, da, 1);
    add_ln<false><<<NB, 256, 0, stream>>>(
        da, dd, nullptr, dec_ln2_g + i * DM, dec_ln2_b + i * DM, dd, nullptr);
    // ffn: dh = dd@W1 (b1+relu folded into FFN2's A read); df = relu(dh+b1)@W2
    skinny_splitk<false><<<dim3(32, 8), 256, 0, stream>>>(
        dd, nullptr, dec_ffn1_w + (size_t)i * WFS, dh, DFF, DM, 64);
    skinny_splitk<true><<<dim3(8, 32), 256, 0, stream>>>(
        dh, dec_ffn1_b + (size_t)i * DFF, dec_ffn2_w + (size_t)i * WFS,
        df, DM, DFF, 64);
    add_ln<false><<<NB, 256, 0, stream>>>(
        df, dd, dec_ffn2_b + (size_t)i * DM,
        dec_ln3_g + i * DM, dec_ln3_b + i * DM, dd, nullptr);
  }

  // ---- output projection ----
  hipMemsetAsync(d_out, 0, (size_t)NB * OUTD * 4, stream);
  skinny_splitk<false><<<dim3(16, 8), 256, 0, stream>>>(
      dd, nullptr, out_w, (float*)d_out, OUTD, DM, 64);
  add_bias_out<<<(NB * OUTD + 255) / 256, 256, 0, stream>>>((float*)d_out, out_b);
}

// Round 4
// 1396.256 us; speedup vs baseline: 6.0858x; 1.2407x over previous
//
#include <hip/hip_runtime.h>
#include <hip/hip_bf16.h>

#define DM 512
#define NH 8
#define DK 64
#define SEQ 512
#define NB 8
#define NL 6
#define DFF 2048
#define OUTD 1000
#define EMB_SCALE 22.627416997969522f
#define PE_C (-0.017988946039015984)   // -ln(10000)/512

typedef __bf16 bf16x8 __attribute__((ext_vector_type(8)));
typedef __bf16 bf16x4 __attribute__((ext_vector_type(4)));
typedef float f32x4 __attribute__((ext_vector_type(4)));

// ---------------- PE table ----------------
__global__ __launch_bounds__(256) void pe_kernel(float* __restrict__ pe) {
  int s = blockIdx.x;
  int d2 = threadIdx.x;
  double div = exp((double)(2 * d2) * PE_C);
  double arg = (double)s * div;
  pe[(size_t)s * DM + 2 * d2] = (float)sin(arg);
  pe[(size_t)s * DM + 2 * d2 + 1] = (float)cos(arg);
}

// ---------------- embedding ----------------
__global__ __launch_bounds__(256) void embed_enc(const int* __restrict__ x,
                                                 const float* __restrict__ emb,
                                                 const float* __restrict__ pe,
                                                 float* __restrict__ e,
                                                 __bf16* __restrict__ eb) {
  int idx = blockIdx.x * 256 + threadIdx.x;
  int d = idx & (DM - 1);
  int bs = idx >> 9;
  int s = bs & (SEQ - 1);
  int tok = x[bs];
  float v = emb[(size_t)tok * DM + d] * EMB_SCALE + pe[(size_t)s * DM + d];
  e[idx] = v;
  eb[idx] = (__bf16)v;
}

__global__ __launch_bounds__(256) void embed_dec(const int* __restrict__ t,
                                                 const float* __restrict__ emb,
                                                 float* __restrict__ dd) {
  int idx = blockIdx.x * 256 + threadIdx.x;
  int d = idx & (DM - 1);
  int b = idx >> 9;
  float pe = (d & 1) ? 1.0f : 0.0f;
  dd[idx] = emb[(size_t)t[b] * DM + d] * EMB_SCALE + pe;
}

// ---------------- weight transpose fp32[K][N] -> bf16[N][K] ----------------
__global__ __launch_bounds__(256) void transpose_w(const float* __restrict__ W,
                                                   __bf16* __restrict__ WT,
                                                   int K, int N) {
  __shared__ float t[32][33];
  size_t off = (size_t)blockIdx.z * K * N;
  W += off; WT += off;
  int k0 = blockIdx.y * 32, n0 = blockIdx.x * 32;
  int tx = threadIdx.x & 7, ty = threadIdx.x >> 3;
  float4 v = *(const float4*)&W[(size_t)(k0 + ty) * N + n0 + tx * 4];
  t[ty][tx * 4 + 0] = v.x; t[ty][tx * 4 + 1] = v.y;
  t[ty][tx * 4 + 2] = v.z; t[ty][tx * 4 + 3] = v.w;
  __syncthreads();
  bf16x4 o;
  o[0] = (__bf16)t[tx * 4 + 0][ty];
  o[1] = (__bf16)t[tx * 4 + 1][ty];
  o[2] = (__bf16)t[tx * 4 + 2][ty];
  o[3] = (__bf16)t[tx * 4 + 3][ty];
  *(bf16x4*)&WT[(size_t)(n0 + ty) * K + k0 + tx * 4] = o;
}

// ---------------- MFMA GEMM (encoder); BN = 128 or 64 ----------------
#define LDSP 72
template <int BN, bool RELU, bool WF32, bool WBF16>
__global__ __launch_bounds__(256) void mfma_gemm(
    const __bf16* __restrict__ A, const __bf16* __restrict__ BT,
    const float* __restrict__ bias, float* __restrict__ C,
    __bf16* __restrict__ Cb, int M, int N, int K,
    long btStride, long bStride, long cStride) {
  int z = blockIdx.z;
  BT += (size_t)z * btStride;
  bias += (size_t)z * bStride;
  if (WF32) C += (size_t)z * cStride;
  if (WBF16) Cb += (size_t)z * cStride;

  constexpr int NI = BN / 32;   // acc columns per wave
  __shared__ __bf16 As[128 * LDSP];
  __shared__ __bf16 Bs[BN * LDSP];

  int tid = threadIdx.x;
  int wave = tid >> 6, lane = tid & 63;
  int wm = wave >> 1, wn = wave & 1;
  int quad = lane >> 4, l16 = lane & 15;
  int m0 = blockIdx.y * 128, n0 = blockIdx.x * BN;

  f32x4 acc[4][NI];
#pragma unroll
  for (int i = 0; i < 4; ++i)
#pragma unroll
    for (int j = 0; j < NI; ++j) acc[i][j] = (f32x4){0.f, 0.f, 0.f, 0.f};

  for (int k0 = 0; k0 < K; k0 += 64) {
#pragma unroll
    for (int j = 0; j < 4; ++j) {
      int c = j * 256 + tid;
      int row = c >> 3, col = (c & 7) * 8;
      *(bf16x8*)&As[row * LDSP + col] =
          *(const bf16x8*)&A[(size_t)(m0 + row) * K + k0 + col];
    }
#pragma unroll
    for (int j = 0; j < BN / 32; ++j) {
      int c = j * 256 + tid;
      int row = c >> 3, col = (c & 7) * 8;
      *(bf16x8*)&Bs[row * LDSP + col] =
          *(const bf16x8*)&BT[(size_t)(n0 + row) * K + k0 + col];
    }
    __syncthreads();
#pragma unroll
    for (int kk = 0; kk < 64; kk += 32) {
      bf16x8 af[4], bf[NI];
#pragma unroll
      for (int i = 0; i < 4; ++i)
        af[i] = *(const bf16x8*)&As[(wm * 64 + i * 16 + l16) * LDSP + kk + quad * 8];
#pragma unroll
      for (int i = 0; i < NI; ++i)
        bf[i] = *(const bf16x8*)&Bs[(wn * (BN / 2) + i * 16 + l16) * LDSP + kk + quad * 8];
#pragma unroll
      for (int mi = 0; mi < 4; ++mi)
#pragma unroll
        for (int ni = 0; ni < NI; ++ni)
          acc[mi][ni] = __builtin_amdgcn_mfma_f32_16x16x32_bf16(
              af[mi], bf[ni], acc[mi][ni], 0, 0, 0);
    }
    __syncthreads();
  }

#pragma unroll
  for (int ni = 0; ni < NI; ++ni) {
    int col = n0 + wn * (BN / 2) + ni * 16 + l16;
    float bv = bias[col];
#pragma unroll
    for (int mi = 0; mi < 4; ++mi) {
#pragma unroll
      for (int r = 0; r < 4; ++r) {
        int row = m0 + wm * 64 + mi * 16 + quad * 4 + r;
        float v = acc[mi][ni][r] + bv;
        if (RELU) v = fmaxf(v, 0.f);
        if (WF32) C[(size_t)row * N + col] = v;
        if (WBF16) Cb[(size_t)row * N + col] = (__bf16)v;
      }
    }
  }
}

// ---------------- MFMA encoder attention ----------------
#define SCP 520
__global__ __launch_bounds__(256) void attn_mfma(const __bf16* __restrict__ QKV,
                                                 float* __restrict__ O) {
  __shared__ __bf16 Sc[16 * SCP];
  __shared__ __bf16 Tt[64 * LDSP];

  const long ACTL = (long)NB * SEQ * DM;
  int tid = threadIdx.x;
  int wave = tid >> 6, lane = tid & 63;
  int quad = lane >> 4, l16 = lane & 15;
  int q0 = blockIdx.x * 16;
  int bh = blockIdx.y, b = bh >> 3, h = bh & 7;
  const __bf16* Q = QKV;
  const __bf16* K = QKV + ACTL;
  const __bf16* V = QKV + 2 * ACTL;
  size_t baseQ = ((size_t)b * SEQ + q0) * DM + h * DK;
  size_t baseKV = ((size_t)b * SEQ) * DM + h * DK;

  bf16x8 af0 = *(const bf16x8*)&Q[baseQ + (size_t)l16 * DM + quad * 8];
  bf16x8 af1 = *(const bf16x8*)&Q[baseQ + (size_t)l16 * DM + 32 + quad * 8];

  for (int kt = 0; kt < 8; ++kt) {
    __syncthreads();
    for (int i = tid; i < 512; i += 256) {
      int key = i >> 3, d8 = (i & 7) * 8;
      *(bf16x8*)&Tt[key * LDSP + d8] =
          *(const bf16x8*)&K[baseKV + (size_t)(kt * 64 + key) * DM + d8];
    }
    __syncthreads();
    f32x4 acc = (f32x4){0.f, 0.f, 0.f, 0.f};
    int krow = wave * 16 + l16;
    bf16x8 b0 = *(const bf16x8*)&Tt[krow * LDSP + quad * 8];
    bf16x8 b1 = *(const bf16x8*)&Tt[krow * LDSP + 32 + quad * 8];
    acc = __builtin_amdgcn_mfma_f32_16x16x32_bf16(af0, b0, acc, 0, 0, 0);
    acc = __builtin_amdgcn_mfma_f32_16x16x32_bf16(af1, b1, acc, 0, 0, 0);
#pragma unroll
    for (int r = 0; r < 4; ++r)
      Sc[(quad * 4 + r) * SCP + kt * 64 + wave * 16 + l16] =
          (__bf16)(acc[r] * 0.125f);
  }
  __syncthreads();

#pragma unroll
  for (int rr = 0; rr < 4; ++rr) {
    int r = wave * 4 + rr;
    float v[8];
    float mx = -1e30f;
#pragma unroll
    for (int j = 0; j < 8; ++j) {
      v[j] = (float)Sc[r * SCP + j * 64 + lane];
      mx = fmaxf(mx, v[j]);
    }
    for (int o = 32; o > 0; o >>= 1) mx = fmaxf(mx, __shfl_xor(mx, o));
    float sum = 0.f;
#pragma unroll
    for (int j = 0; j < 8; ++j) { v[j] = __expf(v[j] - mx); sum += v[j]; }
    for (int o = 32; o > 0; o >>= 1) sum += __shfl_xor(sum, o);
    float inv = 1.f / sum;
#pragma unroll
    for (int j = 0; j < 8; ++j)
      Sc[r * SCP + j * 64 + lane] = (__bf16)(v[j] * inv);
  }

  f32x4 oacc = (f32x4){0.f, 0.f, 0.f, 0.f};
  for (int kt = 0; kt < 8; ++kt) {
    __syncthreads();
    for (int i = tid; i < 512; i += 256) {
      int key = i >> 3, d8 = (i & 7) * 8;
      bf16x8 vv = *(const bf16x8*)&V[baseKV + (size_t)(kt * 64 + key) * DM + d8];
#pragma unroll
      for (int jj = 0; jj < 8; ++jj) Tt[(d8 + jj) * LDSP + key] = vv[jj];
    }
    __syncthreads();
#pragma unroll
    for (int kk = 0; kk < 64; kk += 32) {
      bf16x8 pa = *(const bf16x8*)&Sc[l16 * SCP + kt * 64 + kk + quad * 8];
      bf16x8 vb = *(const bf16x8*)&Tt[(wave * 16 + l16) * LDSP + kk + quad * 8];
      oacc = __builtin_amdgcn_mfma_f32_16x16x32_bf16(pa, vb, oacc, 0, 0, 0);
    }
  }
#pragma unroll
  for (int r = 0; r < 4; ++r)
    O[((size_t)b * SEQ + q0 + quad * 4 + r) * DM + h * DK + wave * 16 + l16] =
        oacc[r];
}

// ---------------- split-K skinny GEMM (decoder, M == 8) ----------------
template <bool RELUA>
__global__ __launch_bounds__(256) void skinny_splitk(
    const float* __restrict__ A, const float* __restrict__ abias,
    const float* __restrict__ W, float* __restrict__ C,
    int N, int K, int Kc) {
  __shared__ float As[8 * 64];        // Kc <= 64
  __shared__ float red[4][8][64];

  int tid = threadIdx.x;
  int kbase = blockIdx.y * Kc;
  for (int i = tid; i < 8 * Kc; i += 256) {
    int r = i / Kc, k = i - r * Kc;
    float v = A[(size_t)r * K + kbase + k];
    if (RELUA) v = fmaxf(v + abias[kbase + k], 0.f);
    As[r * 64 + k] = v;
  }
  __syncthreads();

  int tn = tid & 63, tk = tid >> 6;
  int n = blockIdx.x * 64 + tn;
  float acc[8] = {};
  if (n < N) {
    for (int k = tk; k < Kc; k += 4) {
      float w = W[(size_t)(kbase + k) * N + n];
#pragma unroll
      for (int r = 0; r < 8; ++r) acc[r] += As[r * 64 + k] * w;
    }
  }
#pragma unroll
  for (int r = 0; r < 8; ++r) red[tk][r][tn] = acc[r];
  __syncthreads();
  if (n < N) {
#pragma unroll
    for (int rr = 0; rr < 2; ++rr) {
      int r = tk * 2 + rr;
      float s = red[0][r][tn] + red[1][r][tn] + red[2][r][tn] + red[3][r][tn];
      atomicAdd(&C[(size_t)r * N + n], s);
    }
  }
}

__global__ __launch_bounds__(256) void init_out(float* __restrict__ out,
                                                const float* __restrict__ b) {
  int i = blockIdx.x * 256 + threadIdx.x;
  if (i < NB * OUTD) out[i] = b[i % OUTD];
}

// ---------------- decoder cross-attention: key-split flash ----------------
// grid (8 ksplits, 64 bh), block 256. Partials: pm/pl [64][8], po [64][8][64].
__global__ __launch_bounds__(256) void dec_cross_partial(
    const float* __restrict__ Q, const float* __restrict__ qb,
    const float* __restrict__ K, const float* __restrict__ V,
    float* __restrict__ pm, float* __restrict__ pl, float* __restrict__ po) {
  __shared__ float qs[64];
  __shared__ float red[4][64];
  __shared__ float pr[64];
  __shared__ float msh, lsh;
  int tid = threadIdx.x;
  int ks = blockIdx.x, bh = blockIdx.y;
  int b = bh >> 3, h = bh & 7;
  size_t baseQ = (size_t)b * DM + h * DK;
  size_t baseKV = ((size_t)b * SEQ + ks * 64) * DM + h * DK;

  if (tid < 64) qs[tid] = Q[baseQ + tid] + qb[h * DK + tid];
  __syncthreads();

  int key = tid & 63, sub = tid >> 6;
  const float* kp = &K[baseKV + (size_t)key * DM + sub * 16];
  float acc = 0.f;
#pragma unroll
  for (int j = 0; j < 16; ++j) acc += qs[sub * 16 + j] * kp[j];
  red[sub][key] = acc;
  __syncthreads();

  if (tid < 64) {
    float s = (red[0][tid] + red[1][tid] + red[2][tid] + red[3][tid]) * 0.125f;
    float m = s;
    for (int o = 32; o > 0; o >>= 1) m = fmaxf(m, __shfl_xor(m, o));
    float p = __expf(s - m);
    float l = p;
    for (int o = 32; o > 0; o >>= 1) l += __shfl_xor(l, o);
    pr[tid] = p;
    if (tid == 0) { msh = m; lsh = l; }
  }
  __syncthreads();

  int d = tid & 63;
  const float* vp = &V[baseKV + (size_t)(sub * 16) * DM + d];
  float oa = 0.f;
#pragma unroll
  for (int j = 0; j < 16; ++j) oa += pr[sub * 16 + j] * vp[(size_t)j * DM];
  red[sub][d] = oa;
  __syncthreads();

  if (tid < 64) {
    po[((size_t)bh * 8 + ks) * 64 + tid] =
        red[0][tid] + red[1][tid] + red[2][tid] + red[3][tid];
    if (tid == 0) { pm[bh * 8 + ks] = msh; pl[bh * 8 + ks] = lsh; }
  }
}

__global__ __launch_bounds__(64) void dec_cross_combine(
    const float* __restrict__ pm, const float* __restrict__ pl,
    const float* __restrict__ po, float* __restrict__ O) {
  int bh = blockIdx.x;
  int d = threadIdx.x;
  int b = bh >> 3, h = bh & 7;
  float M = -1e30f;
#pragma unroll
  for (int i = 0; i < 8; ++i) M = fmaxf(M, pm[bh * 8 + i]);
  float L = 0.f, o = 0.f;
#pragma unroll
  for (int i = 0; i < 8; ++i) {
    float w = __expf(pm[bh * 8 + i] - M);
    L += w * pl[bh * 8 + i];
    o += w * po[((size_t)bh * 8 + i) * 64 + d];
  }
  O[(size_t)b * DM + h * DK + d] = o / L;
}

// ---------------- residual + layernorm (optional column bias on x) --------
template <bool WB>
__global__ __launch_bounds__(256) void add_ln(
    const float* __restrict__ x, const float* __restrict__ res,
    const float* __restrict__ cbias,
    const float* __restrict__ g, const float* __restrict__ beta,
    float* __restrict__ y, __bf16* __restrict__ yb) {
  int row = blockIdx.x;
  int tid = threadIdx.x;
  const float* xr = x + (size_t)row * DM;
  const float* rr = res + (size_t)row * DM;
  float b0 = cbias ? cbias[tid] : 0.f;
  float b1 = cbias ? cbias[tid + 256] : 0.f;
  float v0 = xr[tid] + b0 + rr[tid];
  float v1 = xr[tid + 256] + b1 + rr[tid + 256];
  float s = v0 + v1, sq = v0 * v0 + v1 * v1;
  for (int o = 32; o > 0; o >>= 1) {
    s += __shfl_xor(s, o);
    sq += __shfl_xor(sq, o);
  }
  __shared__ float ps[4], pq[4];
  int wv = tid >> 6;
  if ((tid & 63) == 0) { ps[wv] = s; pq[wv] = sq; }
  __syncthreads();
  s = ps[0] + ps[1] + ps[2] + ps[3];
  sq = pq[0] + pq[1] + pq[2] + pq[3];
  float mean = s * (1.f / DM);
  float var = sq * (1.f / DM) - mean * mean;
  float rstd = rsqrtf(var + 1e-5f);
  float o0 = (v0 - mean) * rstd * g[tid] + beta[tid];
  float o1 = (v1 - mean) * rstd * g[tid + 256] + beta[tid + 256];
  y[(size_t)row * DM + tid] = o0;
  y[(size_t)row * DM + tid + 256] = o1;
  if (WB) {
    yb[(size_t)row * DM + tid] = (__bf16)o0;
    yb[(size_t)row * DM + tid + 256] = (__bf16)o1;
  }
}

// ---------------------------------------------------------------------------
extern "C" void kernel_launch(void* const* d_in, const int* in_sizes, int n_in,
                              void* d_out, int out_size, void* d_ws, size_t ws_size,
                              hipStream_t stream) {
  const int* x = (const int*)d_in[0];
  const int* target = (const int*)d_in[1];
  const float* in_emb = (const float*)d_in[2];
  const float* out_emb = (const float*)d_in[3];
  const float* enc_qkv_w = (const float*)d_in[4];
  const float* enc_qkv_b = (const float*)d_in[5];
  const float* enc_ln1_g = (const float*)d_in[6];
  const float* enc_ln1_b = (const float*)d_in[7];
  const float* enc_ffn1_w = (const float*)d_in[8];
  const float* enc_ffn1_b = (const float*)d_in[9];
  const float* enc_ffn2_w = (const float*)d_in[10];
  const float* enc_ffn2_b = (const float*)d_in[11];
  const float* enc_ln2_g = (const float*)d_in[12];
  const float* enc_ln2_b = (const float*)d_in[13];
  const float* dec_qkv1_w = (const float*)d_in[14];
  const float* dec_qkv1_b = (const float*)d_in[15];
  const float* dec_ln1_g = (const float*)d_in[16];
  const float* dec_ln1_b = (const float*)d_in[17];
  const float* dec_qkv2_w = (const float*)d_in[18];
  const float* dec_qkv2_b = (const float*)d_in[19];
  const float* dec_ln2_g = (const float*)d_in[20];
  const float* dec_ln2_b = (const float*)d_in[21];
  const float* dec_ffn1_w = (const float*)d_in[22];
  const float* dec_ffn1_b = (const float*)d_in[23];
  const float* dec_ffn2_w = (const float*)d_in[24];
  const float* dec_ffn2_b = (const float*)d_in[25];
  const float* dec_ln3_g = (const float*)d_in[26];
  const float* dec_ln3_b = (const float*)d_in[27];
  const float* out_w = (const float*)d_in[28];
  const float* out_b = (const float*)d_in[29];

  const long ACTL = (long)NB * SEQ * DM;           // 2M elems
  const int M = NB * SEQ;                           // 4096

  char* p = (char*)d_ws;
  float* e = (float*)p;            p += ACTL * 4;
  float* tb = (float*)p;           p += ACTL * 4;
  float* kvf = (float*)p;          p += 2 * ACTL * 4;
  float* pe = (float*)p;           p += (long)SEQ * DM * 4;
  float* dd = (float*)p;           p += NB * DM * 4;
  // decoder scratch (dqv..df contiguous for the single memset)
  float* dqv = (float*)p;          p += NB * DM * 4;
  float* dqq = (float*)p;          p += NB * DM * 4;
  float* dh = (float*)p;           p += NB * DFF * 4;
  float* df = (float*)p;           p += NB * DM * 4;
  float* da = (float*)p;           p += NB * DM * 4;
  float* pm = (float*)p;           p += 64 * 8 * 4;
  float* pl = (float*)p;           p += 64 * 8 * 4;
  float* po = (float*)p;           p += 64 * 8 * 64 * 4;
  p = (char*)(((uintptr_t)p + 255) & ~(uintptr_t)255);
  __bf16* eb = (__bf16*)p;         p += ACTL * 2;
  __bf16* qkvb = (__bf16*)p;       p += 3 * ACTL * 2;
  __bf16* hbb = (__bf16*)p;        p += (long)M * DFF * 2;
  __bf16* wtq = (__bf16*)p;        p += 18L * DM * DM * 2;
  __bf16* wtf1 = (__bf16*)p;       p += 6L * DM * DFF * 2;
  __bf16* wtf2 = (__bf16*)p;       p += 6L * DFF * DM * 2;
  __bf16* wtd = (__bf16*)p;        p += 18L * DM * DM * 2;

  const long WQS = (long)DM * DM;
  const long WFS = (long)DM * DFF;
  const size_t DEC_ZERO_BYTES = (size_t)NB * (DM + DM + DFF + DM) * 4;

  // ---- one-time prep ----
  pe_kernel<<<SEQ, 256, 0, stream>>>(pe);
  transpose_w<<<dim3(16, 16, 18), 256, 0, stream>>>(enc_qkv_w, wtq, DM, DM);
  transpose_w<<<dim3(64, 16, 6), 256, 0, stream>>>(enc_ffn1_w, wtf1, DM, DFF);
  transpose_w<<<dim3(16, 64, 6), 256, 0, stream>>>(enc_ffn2_w, wtf2, DFF, DM);
  transpose_w<<<dim3(16, 16, 18), 256, 0, stream>>>(dec_qkv2_w, wtd, DM, DM);

  // ---- encoder ----
  embed_enc<<<(M * DM) / 256, 256, 0, stream>>>(x, in_emb, pe, e, eb);
  for (int i = 0; i < NL; ++i) {
    mfma_gemm<128, false, false, true><<<dim3(4, 32, 3), 256, 0, stream>>>(
        eb, wtq + (size_t)i * 3 * WQS, enc_qkv_b + (size_t)i * 3 * DM,
        nullptr, qkvb, M, DM, DM, WQS, DM, ACTL);
    attn_mfma<<<dim3(SEQ / 16, NB * NH), 256, 0, stream>>>(qkvb, tb);
    add_ln<true><<<M, 256, 0, stream>>>(tb, e, nullptr, enc_ln1_g + i * DM,
                                        enc_ln1_b + i * DM, e, eb);
    mfma_gemm<128, true, false, true><<<dim3(16, 32, 1), 256, 0, stream>>>(
        eb, wtf1 + (size_t)i * WFS, enc_ffn1_b + (size_t)i * DFF,
        nullptr, hbb, M, DFF, DM, 0, 0, 0);
    mfma_gemm<64, false, true, false><<<dim3(8, 32, 1), 256, 0, stream>>>(
        hbb, wtf2 + (size_t)i * WFS, enc_ffn2_b + (size_t)i * DM,
        tb, nullptr, M, DM, DFF, 0, 0, 0);
    add_ln<true><<<M, 256, 0, stream>>>(tb, e, nullptr, enc_ln2_g + i * DM,
                                        enc_ln2_b + i * DM, e, eb);
  }

  // ---- decoder (seq len 1) ----
  embed_dec<<<(NB * DM) / 256, 256, 0, stream>>>(target, out_emb, dd);
  for (int i = 0; i < NL; ++i) {
    hipMemsetAsync(dqv, 0, DEC_ZERO_BYTES, stream);
    // self-attn (softmax over 1 elem == 1 -> output is V); bias folded in add_ln
    skinny_splitk<false><<<dim3(8, 32), 256, 0, stream>>>(
        dd, nullptr, dec_qkv1_w + ((size_t)i * 3 + 2) * WQS, dqv, DM, DM, 16);
    add_ln<false><<<NB, 256, 0, stream>>>(
        dqv, dd, dec_qkv1_b + ((size_t)i * 3 + 2) * DM,
        dec_ln1_g + i * DM, dec_ln1_b + i * DM, dd, nullptr);
    // cross attention: Q (bias folded into partial), K/V via mfma
    skinny_splitk<false><<<dim3(8, 32), 256, 0, stream>>>(
        dd, nullptr, dec_qkv2_w + ((size_t)i * 3 + 0) * WQS, dqq, DM, DM, 16);
    mfma_gemm<128, false, true, false><<<dim3(4, 32, 2), 256, 0, stream>>>(
        eb, wtd + ((size_t)i * 3 + 1) * WQS, dec_qkv2_b + ((size_t)i * 3 + 1) * DM,
        kvf, nullptr, M, DM, DM, WQS, DM, ACTL);
    dec_cross_partial<<<dim3(8, 64), 256, 0, stream>>>(
        dqq, dec_qkv2_b + ((size_t)i * 3 + 0) * DM, kvf, kvf + ACTL, pm, pl, po);
    dec_cross_combine<<<64, 64, 0, stream>>>(pm, pl, po, da);
    add_ln<false><<<NB, 256, 0, stream>>>(
        da, dd, nullptr, dec_ln2_g + i * DM, dec_ln2_b + i * DM, dd, nullptr);
    // ffn
    skinny_splitk<false><<<dim3(32, 8), 256, 0, stream>>>(
        dd, nullptr, dec_ffn1_w + (size_t)i * WFS, dh, DFF, DM, 64);
    skinny_splitk<true><<<dim3(8, 32), 256, 0, stream>>>(
        dh, dec_ffn1_b + (size_t)i * DFF, dec_ffn2_w + (size_t)i * WFS,
        df, DM, DFF, 64);
    add_ln<false><<<NB, 256, 0, stream>>>(
        df, dd, dec_ffn2_b + (size_t)i * DM,
        dec_ln3_g + i * DM, dec_ln3_b + i * DM, dd, nullptr);
  }

  // ---- output projection (bias-init + atomic split-K) ----
  init_out<<<(NB * OUTD + 255) / 256, 256, 0, stream>>>((float*)d_out, out_b);
  skinny_splitk<false><<<dim3(16, 16), 256, 0, stream>>>(
      dd, nullptr, out_w, (float*)d_out, OUTD, DM, 32);
}

// Round 5
// 1234.333 us; speedup vs baseline: 6.8841x; 1.1312x over previous
//
#include <hip/hip_runtime.h>
#include <hip/hip_bf16.h>

#define DM 512
#define NH 8
#define DK 64
#define SEQ 512
#define NB 8
#define NL 6
#define DFF 2048
#define OUTD 1000
#define EMB_SCALE 22.627416997969522f
#define PE_C (-0.017988946039015984)   // -ln(10000)/512

typedef __bf16 bf16x8 __attribute__((ext_vector_type(8)));
typedef __bf16 bf16x4 __attribute__((ext_vector_type(4)));
typedef float f32x4 __attribute__((ext_vector_type(4)));

// async global->LDS, 16B per lane; LDS dest = wave-uniform base + lane*16
__device__ __forceinline__ void load16_lds(const __bf16* g, __bf16* l) {
  __builtin_amdgcn_global_load_lds(
      (const __attribute__((address_space(1))) void*)g,
      (__attribute__((address_space(3))) void*)l, 16, 0, 0);
}

// ---------------- PE table ----------------
__global__ __launch_bounds__(256) void pe_kernel(float* __restrict__ pe) {
  int s = blockIdx.x;
  int d2 = threadIdx.x;
  double div = exp((double)(2 * d2) * PE_C);
  double arg = (double)s * div;
  pe[(size_t)s * DM + 2 * d2] = (float)sin(arg);
  pe[(size_t)s * DM + 2 * d2 + 1] = (float)cos(arg);
}

// ---------------- embedding ----------------
__global__ __launch_bounds__(256) void embed_enc(const int* __restrict__ x,
                                                 const float* __restrict__ emb,
                                                 const float* __restrict__ pe,
                                                 float* __restrict__ e,
                                                 __bf16* __restrict__ eb) {
  int idx = blockIdx.x * 256 + threadIdx.x;
  int d = idx & (DM - 1);
  int bs = idx >> 9;
  int s = bs & (SEQ - 1);
  int tok = x[bs];
  float v = emb[(size_t)tok * DM + d] * EMB_SCALE + pe[(size_t)s * DM + d];
  e[idx] = v;
  eb[idx] = (__bf16)v;
}

__global__ __launch_bounds__(256) void embed_dec(const int* __restrict__ t,
                                                 const float* __restrict__ emb,
                                                 float* __restrict__ dd) {
  int idx = blockIdx.x * 256 + threadIdx.x;
  int d = idx & (DM - 1);
  int b = idx >> 9;
  float pe = (d & 1) ? 1.0f : 0.0f;
  dd[idx] = emb[(size_t)t[b] * DM + d] * EMB_SCALE + pe;
}

// ---------------- weight transpose fp32[K][N] -> bf16[N][K] ----------------
__global__ __launch_bounds__(256) void transpose_w(const float* __restrict__ W,
                                                   __bf16* __restrict__ WT,
                                                   int K, int N) {
  __shared__ float t[32][33];
  size_t off = (size_t)blockIdx.z * K * N;
  W += off; WT += off;
  int k0 = blockIdx.y * 32, n0 = blockIdx.x * 32;
  int tx = threadIdx.x & 7, ty = threadIdx.x >> 3;
  float4 v = *(const float4*)&W[(size_t)(k0 + ty) * N + n0 + tx * 4];
  t[ty][tx * 4 + 0] = v.x; t[ty][tx * 4 + 1] = v.y;
  t[ty][tx * 4 + 2] = v.z; t[ty][tx * 4 + 3] = v.w;
  __syncthreads();
  bf16x4 o;
  o[0] = (__bf16)t[tx * 4 + 0][ty];
  o[1] = (__bf16)t[tx * 4 + 1][ty];
  o[2] = (__bf16)t[tx * 4 + 2][ty];
  o[3] = (__bf16)t[tx * 4 + 3][ty];
  *(bf16x4*)&WT[(size_t)(n0 + ty) * K + k0 + tx * 4] = o;
}

// ---------------- MFMA GEMM (global_load_lds staging, swizzled LDS) --------
// A bf16 [M][K], BT bf16 [N][K]; tile 128 x BN, BK=64.
// LDS layout: row-major pitch 64, 16B chunk c of row r holds global chunk c^(r&7).
template <int BN, bool RELU, bool WF32, bool WBF16, bool TRV>
__global__ __launch_bounds__(256) void mfma_gemm(
    const __bf16* __restrict__ A, const __bf16* __restrict__ BT,
    const float* __restrict__ bias, float* __restrict__ C,
    __bf16* __restrict__ Cb, __bf16* __restrict__ Vt, int M, int N, int K,
    long btStride, long bStride, long cStride) {
  int z = blockIdx.z;
  BT += (size_t)z * btStride;
  bias += (size_t)z * bStride;
  if (WF32) C += (size_t)z * cStride;
  if (WBF16) Cb += (size_t)z * cStride;

  constexpr int NI = BN / 32;
  __shared__ __bf16 As[128 * 64];
  __shared__ __bf16 Bs[BN * 64];

  int tid = threadIdx.x;
  int wave = tid >> 6, lane = tid & 63;
  int wm = wave >> 1, wn = wave & 1;
  int quad = lane >> 4, l16 = lane & 15;
  int rlane = lane >> 3, c8 = lane & 7;
  int m0 = blockIdx.y * 128, n0 = blockIdx.x * BN;
  int gcol = ((c8 ^ rlane) * 8);   // swizzled source chunk (row&7 == rlane)

  f32x4 acc[4][NI];
#pragma unroll
  for (int i = 0; i < 4; ++i)
#pragma unroll
    for (int j = 0; j < NI; ++j) acc[i][j] = (f32x4){0.f, 0.f, 0.f, 0.f};

  for (int k0 = 0; k0 < K; k0 += 64) {
    __syncthreads();
#pragma unroll
    for (int j = 0; j < 4; ++j) {
      int row = j * 32 + wave * 8 + rlane;
      load16_lds(&A[(size_t)(m0 + row) * K + k0 + gcol],
                 &As[(j * 32 + wave * 8) * 64]);
    }
#pragma unroll
    for (int j = 0; j < BN / 32; ++j) {
      int row = j * 32 + wave * 8 + rlane;
      load16_lds(&BT[(size_t)(n0 + row) * K + k0 + gcol],
                 &Bs[(j * 32 + wave * 8) * 64]);
    }
    __syncthreads();
#pragma unroll
    for (int kk = 0; kk < 64; kk += 32) {
      bf16x8 af[4], bf[NI];
#pragma unroll
      for (int i = 0; i < 4; ++i) {
        int row = wm * 64 + i * 16 + l16;
        af[i] = *(const bf16x8*)&As[row * 64 + ((((kk >> 3) + quad) ^ (row & 7)) * 8)];
      }
#pragma unroll
      for (int i = 0; i < NI; ++i) {
        int row = wn * (BN / 2) + i * 16 + l16;
        bf[i] = *(const bf16x8*)&Bs[row * 64 + ((((kk >> 3) + quad) ^ (row & 7)) * 8)];
      }
#pragma unroll
      for (int mi = 0; mi < 4; ++mi)
#pragma unroll
        for (int ni = 0; ni < NI; ++ni)
          acc[mi][ni] = __builtin_amdgcn_mfma_f32_16x16x32_bf16(
              af[mi], bf[ni], acc[mi][ni], 0, 0, 0);
    }
  }

#pragma unroll
  for (int ni = 0; ni < NI; ++ni) {
    int col = n0 + wn * (BN / 2) + ni * 16 + l16;
    float bv = bias[col];
    if (TRV && z == 2) {
      // write V transposed: Vt[(b*512 + col)][s], 4 consecutive s per lane
      int b = m0 >> 9;
#pragma unroll
      for (int mi = 0; mi < 4; ++mi) {
        int srow = (m0 & 511) + wm * 64 + mi * 16 + quad * 4;
        bf16x4 pk;
#pragma unroll
        for (int r = 0; r < 4; ++r) pk[r] = (__bf16)(acc[mi][ni][r] + bv);
        *(bf16x4*)&Vt[((size_t)(b * 512 + col)) * 512 + srow] = pk;
      }
    } else {
#pragma unroll
      for (int mi = 0; mi < 4; ++mi) {
#pragma unroll
        for (int r = 0; r < 4; ++r) {
          int row = m0 + wm * 64 + mi * 16 + quad * 4 + r;
          float v = acc[mi][ni][r] + bv;
          if (RELU) v = fmaxf(v, 0.f);
          if (WF32) C[(size_t)row * N + col] = v;
          if (WBF16) Cb[(size_t)row * N + col] = (__bf16)v;
        }
      }
    }
  }
}

// ---------------- MFMA encoder attention (K natural, V pre-transposed) -----
#define SCP 520
__global__ __launch_bounds__(256) void attn_mfma(const __bf16* __restrict__ QKV,
                                                 const __bf16* __restrict__ Vt,
                                                 float* __restrict__ O) {
  __shared__ __bf16 Sc[16 * SCP];
  __shared__ __bf16 Tt[64 * 64];

  const long ACTL = (long)NB * SEQ * DM;
  int tid = threadIdx.x;
  int wave = tid >> 6, lane = tid & 63;
  int quad = lane >> 4, l16 = lane & 15;
  int rlane = lane >> 3, c8 = lane & 7;
  int q0 = blockIdx.x * 16;
  int bh = blockIdx.y, b = bh >> 3, h = bh & 7;
  const __bf16* Q = QKV;
  const __bf16* Kp = QKV + ACTL;
  size_t baseQ = ((size_t)b * SEQ + q0) * DM + h * DK;
  size_t baseK = ((size_t)b * SEQ) * DM + h * DK;
  const __bf16* VtB = Vt + ((size_t)(b * 512 + h * 64)) * 512;
  int gcol = (c8 ^ rlane) * 8;

  bf16x8 af0 = *(const bf16x8*)&Q[baseQ + (size_t)l16 * DM + quad * 8];
  bf16x8 af1 = *(const bf16x8*)&Q[baseQ + (size_t)l16 * DM + 32 + quad * 8];

  // ---- phase 1: S = Q K^T / 8 ----
  for (int kt = 0; kt < 8; ++kt) {
    __syncthreads();
#pragma unroll
    for (int j = 0; j < 2; ++j) {
      int row = j * 32 + wave * 8 + rlane;
      load16_lds(&Kp[baseK + (size_t)(kt * 64 + row) * DM + gcol],
                 &Tt[(j * 32 + wave * 8) * 64]);
    }
    __syncthreads();
    f32x4 acc = (f32x4){0.f, 0.f, 0.f, 0.f};
    int krow = wave * 16 + l16, sw = krow & 7;
    bf16x8 b0 = *(const bf16x8*)&Tt[krow * 64 + ((quad ^ sw) * 8)];
    bf16x8 b1 = *(const bf16x8*)&Tt[krow * 64 + (((4 + quad) ^ sw) * 8)];
    acc = __builtin_amdgcn_mfma_f32_16x16x32_bf16(af0, b0, acc, 0, 0, 0);
    acc = __builtin_amdgcn_mfma_f32_16x16x32_bf16(af1, b1, acc, 0, 0, 0);
#pragma unroll
    for (int r = 0; r < 4; ++r)
      Sc[(quad * 4 + r) * SCP + kt * 64 + wave * 16 + l16] =
          (__bf16)(acc[r] * 0.125f);
  }
  __syncthreads();

  // ---- softmax (wave handles 4 rows) ----
#pragma unroll
  for (int rr = 0; rr < 4; ++rr) {
    int r = wave * 4 + rr;
    float v[8];
    float mx = -1e30f;
#pragma unroll
    for (int j = 0; j < 8; ++j) {
      v[j] = (float)Sc[r * SCP + j * 64 + lane];
      mx = fmaxf(mx, v[j]);
    }
    for (int o = 32; o > 0; o >>= 1) mx = fmaxf(mx, __shfl_xor(mx, o));
    float sum = 0.f;
#pragma unroll
    for (int j = 0; j < 8; ++j) { v[j] = __expf(v[j] - mx); sum += v[j]; }
    for (int o = 32; o > 0; o >>= 1) sum += __shfl_xor(sum, o);
    float inv = 1.f / sum;
#pragma unroll
    for (int j = 0; j < 8; ++j)
      Sc[r * SCP + j * 64 + lane] = (__bf16)(v[j] * inv);
  }

  // ---- phase 2: O = P V ; wave owns d-slice [wave*16, +16) ----
  f32x4 oacc = (f32x4){0.f, 0.f, 0.f, 0.f};
  for (int kt = 0; kt < 8; ++kt) {
    __syncthreads();
#pragma unroll
    for (int j = 0; j < 2; ++j) {
      int row = j * 32 + wave * 8 + rlane;          // d index
      load16_lds(&VtB[(size_t)row * 512 + kt * 64 + gcol],
                 &Tt[(j * 32 + wave * 8) * 64]);
    }
    __syncthreads();
    int drow = wave * 16 + l16, sw = drow & 7;
#pragma unroll
    for (int kk = 0; kk < 64; kk += 32) {
      bf16x8 pa = *(const bf16x8*)&Sc[l16 * SCP + kt * 64 + kk + quad * 8];
      bf16x8 vb = *(const bf16x8*)&Tt[drow * 64 + ((((kk >> 3) + quad) ^ sw) * 8)];
      oacc = __builtin_amdgcn_mfma_f32_16x16x32_bf16(pa, vb, oacc, 0, 0, 0);
    }
  }
#pragma unroll
  for (int r = 0; r < 4; ++r)
    O[((size_t)b * SEQ + q0 + quad * 4 + r) * DM + h * DK + wave * 16 + l16] =
        oacc[r];
}

// ---------------- split-K skinny GEMM (decoder, M == 8) ----------------
template <bool RELUA>
__global__ __launch_bounds__(256) void skinny_splitk(
    const float* __restrict__ A, const float* __restrict__ abias,
    const float* __restrict__ W, float* __restrict__ C,
    int N, int K, int Kc) {
  __shared__ float As[8 * 64];        // Kc <= 64
  __shared__ float red[4][8][64];

  int tid = threadIdx.x;
  int kbase = blockIdx.y * Kc;
  for (int i = tid; i < 8 * Kc; i += 256) {
    int r = i / Kc, k = i - r * Kc;
    float v = A[(size_t)r * K + kbase + k];
    if (RELUA) v = fmaxf(v + abias[kbase + k], 0.f);
    As[r * 64 + k] = v;
  }
  __syncthreads();

  int tn = tid & 63, tk = tid >> 6;
  int n = blockIdx.x * 64 + tn;
  float acc[8] = {};
  if (n < N) {
    for (int k = tk; k < Kc; k += 4) {
      float w = W[(size_t)(kbase + k) * N + n];
#pragma unroll
      for (int r = 0; r < 8; ++r) acc[r] += As[r * 64 + k] * w;
    }
  }
#pragma unroll
  for (int r = 0; r < 8; ++r) red[tk][r][tn] = acc[r];
  __syncthreads();
  if (n < N) {
#pragma unroll
    for (int rr = 0; rr < 2; ++rr) {
      int r = tk * 2 + rr;
      float s = red[0][r][tn] + red[1][r][tn] + red[2][r][tn] + red[3][r][tn];
      atomicAdd(&C[(size_t)r * N + n], s);
    }
  }
}

__global__ __launch_bounds__(256) void init_out(float* __restrict__ out,
                                                const float* __restrict__ b) {
  int i = blockIdx.x * 256 + threadIdx.x;
  if (i < NB * OUTD) out[i] = b[i % OUTD];
}

// ---------------- decoder cross-attention: key-split flash ----------------
__global__ __launch_bounds__(256) void dec_cross_partial(
    const float* __restrict__ Q, const float* __restrict__ qb,
    const float* __restrict__ K, const float* __restrict__ V,
    float* __restrict__ pm, float* __restrict__ pl, float* __restrict__ po) {
  __shared__ float qs[64];
  __shared__ float red[4][64];
  __shared__ float pr[64];
  __shared__ float msh, lsh;
  int tid = threadIdx.x;
  int ks = blockIdx.x, bh = blockIdx.y;
  int b = bh >> 3, h = bh & 7;
  size_t baseQ = (size_t)b * DM + h * DK;
  size_t baseKV = ((size_t)b * SEQ + ks * 64) * DM + h * DK;

  if (tid < 64) qs[tid] = Q[baseQ + tid] + qb[h * DK + tid];
  __syncthreads();

  int key = tid & 63, sub = tid >> 6;
  const float* kp = &K[baseKV + (size_t)key * DM + sub * 16];
  float acc = 0.f;
#pragma unroll
  for (int j = 0; j < 16; ++j) acc += qs[sub * 16 + j] * kp[j];
  red[sub][key] = acc;
  __syncthreads();

  if (tid < 64) {
    float s = (red[0][tid] + red[1][tid] + red[2][tid] + red[3][tid]) * 0.125f;
    float m = s;
    for (int o = 32; o > 0; o >>= 1) m = fmaxf(m, __shfl_xor(m, o));
    float p = __expf(s - m);
    float l = p;
    for (int o = 32; o > 0; o >>= 1) l += __shfl_xor(l, o);
    pr[tid] = p;
    if (tid == 0) { msh = m; lsh = l; }
  }
  __syncthreads();

  int d = tid & 63;
  const float* vp = &V[baseKV + (size_t)(sub * 16) * DM + d];
  float oa = 0.f;
#pragma unroll
  for (int j = 0; j < 16; ++j) oa += pr[sub * 16 + j] * vp[(size_t)j * DM];
  red[sub][d] = oa;
  __syncthreads();

  if (tid < 64) {
    po[((size_t)bh * 8 + ks) * 64 + tid] =
        red[0][tid] + red[1][tid] + red[2][tid] + red[3][tid];
    if (tid == 0) { pm[bh * 8 + ks] = msh; pl[bh * 8 + ks] = lsh; }
  }
}

__global__ __launch_bounds__(64) void dec_cross_combine(
    const float* __restrict__ pm, const float* __restrict__ pl,
    const float* __restrict__ po, float* __restrict__ O) {
  int bh = blockIdx.x;
  int d = threadIdx.x;
  int b = bh >> 3, h = bh & 7;
  float M = -1e30f;
#pragma unroll
  for (int i = 0; i < 8; ++i) M = fmaxf(M, pm[bh * 8 + i]);
  float L = 0.f, o = 0.f;
#pragma unroll
  for (int i = 0; i < 8; ++i) {
    float w = __expf(pm[bh * 8 + i] - M);
    L += w * pl[bh * 8 + i];
    o += w * po[((size_t)bh * 8 + i) * 64 + d];
  }
  O[(size_t)b * DM + h * DK + d] = o / L;
}

// ---------------- residual + layernorm (optional column bias on x) --------
template <bool WB>
__global__ __launch_bounds__(256) void add_ln(
    const float* __restrict__ x, const float* __restrict__ res,
    const float* __restrict__ cbias,
    const float* __restrict__ g, const float* __restrict__ beta,
    float* __restrict__ y, __bf16* __restrict__ yb) {
  int row = blockIdx.x;
  int tid = threadIdx.x;
  const float* xr = x + (size_t)row * DM;
  const float* rr = res + (size_t)row * DM;
  float b0 = cbias ? cbias[tid] : 0.f;
  float b1 = cbias ? cbias[tid + 256] : 0.f;
  float v0 = xr[tid] + b0 + rr[tid];
  float v1 = xr[tid + 256] + b1 + rr[tid + 256];
  float s = v0 + v1, sq = v0 * v0 + v1 * v1;
  for (int o = 32; o > 0; o >>= 1) {
    s += __shfl_xor(s, o);
    sq += __shfl_xor(sq, o);
  }
  __shared__ float ps[4], pq[4];
  int wv = tid >> 6;
  if ((tid & 63) == 0) { ps[wv] = s; pq[wv] = sq; }
  __syncthreads();
  s = ps[0] + ps[1] + ps[2] + ps[3];
  sq = pq[0] + pq[1] + pq[2] + pq[3];
  float mean = s * (1.f / DM);
  float var = sq * (1.f / DM) - mean * mean;
  float rstd = rsqrtf(var + 1e-5f);
  float o0 = (v0 - mean) * rstd * g[tid] + beta[tid];
  float o1 = (v1 - mean) * rstd * g[tid + 256] + beta[tid + 256];
  y[(size_t)row * DM + tid] = o0;
  y[(size_t)row * DM + tid + 256] = o1;
  if (WB) {
    yb[(size_t)row * DM + tid] = (__bf16)o0;
    yb[(size_t)row * DM + tid + 256] = (__bf16)o1;
  }
}

// ---------------------------------------------------------------------------
extern "C" void kernel_launch(void* const* d_in, const int* in_sizes, int n_in,
                              void* d_out, int out_size, void* d_ws, size_t ws_size,
                              hipStream_t stream) {
  const int* x = (const int*)d_in[0];
  const int* target = (const int*)d_in[1];
  const float* in_emb = (const float*)d_in[2];
  const float* out_emb = (const float*)d_in[3];
  const float* enc_qkv_w = (const float*)d_in[4];
  const float* enc_qkv_b = (const float*)d_in[5];
  const float* enc_ln1_g = (const float*)d_in[6];
  const float* enc_ln1_b = (const float*)d_in[7];
  const float* enc_ffn1_w = (const float*)d_in[8];
  const float* enc_ffn1_b = (const float*)d_in[9];
  const float* enc_ffn2_w = (const float*)d_in[10];
  const float* enc_ffn2_b = (const float*)d_in[11];
  const float* enc_ln2_g = (const float*)d_in[12];
  const float* enc_ln2_b = (const float*)d_in[13];
  const float* dec_qkv1_w = (const float*)d_in[14];
  const float* dec_qkv1_b = (const float*)d_in[15];
  const float* dec_ln1_g = (const float*)d_in[16];
  const float* dec_ln1_b = (const float*)d_in[17];
  const float* dec_qkv2_w = (const float*)d_in[18];
  const float* dec_qkv2_b = (const float*)d_in[19];
  const float* dec_ln2_g = (const float*)d_in[20];
  const float* dec_ln2_b = (const float*)d_in[21];
  const float* dec_ffn1_w = (const float*)d_in[22];
  const float* dec_ffn1_b = (const float*)d_in[23];
  const float* dec_ffn2_w = (const float*)d_in[24];
  const float* dec_ffn2_b = (const float*)d_in[25];
  const float* dec_ln3_g = (const float*)d_in[26];
  const float* dec_ln3_b = (const float*)d_in[27];
  const float* out_w = (const float*)d_in[28];
  const float* out_b = (const float*)d_in[29];

  const long ACTL = (long)NB * SEQ * DM;           // 2M elems
  const int M = NB * SEQ;                           // 4096

  char* p = (char*)d_ws;
  float* e = (float*)p;            p += ACTL * 4;
  float* tb = (float*)p;           p += ACTL * 4;
  float* kvf = (float*)p;          p += 2 * ACTL * 4;
  float* pe = (float*)p;           p += (long)SEQ * DM * 4;
  float* dd = (float*)p;           p += NB * DM * 4;
  float* dqv = (float*)p;          p += NB * DM * 4;
  float* dqq = (float*)p;          p += NB * DM * 4;
  float* dh = (float*)p;           p += NB * DFF * 4;
  float* df = (float*)p;           p += NB * DM * 4;
  float* da = (float*)p;           p += NB * DM * 4;
  float* pm = (float*)p;           p += 64 * 8 * 4;
  float* pl = (float*)p;           p += 64 * 8 * 4;
  float* po = (float*)p;           p += 64 * 8 * 64 * 4;
  p = (char*)(((uintptr_t)p + 255) & ~(uintptr_t)255);
  __bf16* eb = (__bf16*)p;         p += ACTL * 2;
  __bf16* qkvb = (__bf16*)p;       p += 3 * ACTL * 2;   // Q,K normal; slice 2 = V^T
  __bf16* hbb = (__bf16*)p;        p += (long)M * DFF * 2;
  __bf16* wtq = (__bf16*)p;        p += 18L * DM * DM * 2;
  __bf16* wtf1 = (__bf16*)p;       p += 6L * DM * DFF * 2;
  __bf16* wtf2 = (__bf16*)p;       p += 6L * DFF * DM * 2;
  __bf16* wtd = (__bf16*)p;        p += 18L * DM * DM * 2;

  __bf16* vtb = qkvb + 2 * ACTL;   // V^T lives in the z=2 slice

  const long WQS = (long)DM * DM;
  const long WFS = (long)DM * DFF;
  const size_t DEC_ZERO_BYTES = (size_t)NB * (DM + DM + DFF + DM) * 4;

  // ---- one-time prep ----
  pe_kernel<<<SEQ, 256, 0, stream>>>(pe);
  transpose_w<<<dim3(16, 16, 18), 256, 0, stream>>>(enc_qkv_w, wtq, DM, DM);
  transpose_w<<<dim3(64, 16, 6), 256, 0, stream>>>(enc_ffn1_w, wtf1, DM, DFF);
  transpose_w<<<dim3(16, 64, 6), 256, 0, stream>>>(enc_ffn2_w, wtf2, DFF, DM);
  transpose_w<<<dim3(16, 16, 18), 256, 0, stream>>>(dec_qkv2_w, wtd, DM, DM);

  // ---- encoder ----
  embed_enc<<<(M * DM) / 256, 256, 0, stream>>>(x, in_emb, pe, e, eb);
  for (int i = 0; i < NL; ++i) {
    mfma_gemm<128, false, false, true, true><<<dim3(4, 32, 3), 256, 0, stream>>>(
        eb, wtq + (size_t)i * 3 * WQS, enc_qkv_b + (size_t)i * 3 * DM,
        nullptr, qkvb, vtb, M, DM, DM, WQS, DM, ACTL);
    attn_mfma<<<dim3(SEQ / 16, NB * NH), 256, 0, stream>>>(qkvb, vtb, tb);
    add_ln<true><<<M, 256, 0, stream>>>(tb, e, nullptr, enc_ln1_g + i * DM,
                                        enc_ln1_b + i * DM, e, eb);
    mfma_gemm<128, true, false, true, false><<<dim3(16, 32, 1), 256, 0, stream>>>(
        eb, wtf1 + (size_t)i * WFS, enc_ffn1_b + (size_t)i * DFF,
        nullptr, hbb, nullptr, M, DFF, DM, 0, 0, 0);
    mfma_gemm<64, false, true, false, false><<<dim3(8, 32, 1), 256, 0, stream>>>(
        hbb, wtf2 + (size_t)i * WFS, enc_ffn2_b + (size_t)i * DM,
        tb, nullptr, nullptr, M, DM, DFF, 0, 0, 0);
    add_ln<true><<<M, 256, 0, stream>>>(tb, e, nullptr, enc_ln2_g + i * DM,
                                        enc_ln2_b + i * DM, e, eb);
  }

  // ---- decoder (seq len 1) ----
  embed_dec<<<(NB * DM) / 256, 256, 0, stream>>>(target, out_emb, dd);
  for (int i = 0; i < NL; ++i) {
    hipMemsetAsync(dqv, 0, DEC_ZERO_BYTES, stream);
    skinny_splitk<false><<<dim3(8, 32), 256, 0, stream>>>(
        dd, nullptr, dec_qkv1_w + ((size_t)i * 3 + 2) * WQS, dqv, DM, DM, 16);
    add_ln<false><<<NB, 256, 0, stream>>>(
        dqv, dd, dec_qkv1_b + ((size_t)i * 3 + 2) * DM,
        dec_ln1_g + i * DM, dec_ln1_b + i * DM, dd, nullptr);
    skinny_splitk<false><<<dim3(8, 32), 256, 0, stream>>>(
        dd, nullptr, dec_qkv2_w + ((size_t)i * 3 + 0) * WQS, dqq, DM, DM, 16);
    mfma_gemm<128, false, true, false, false><<<dim3(4, 32, 2), 256, 0, stream>>>(
        eb, wtd + ((size_t)i * 3 + 1) * WQS, dec_qkv2_b + ((size_t)i * 3 + 1) * DM,
        kvf, nullptr, nullptr, M, DM, DM, WQS, DM, ACTL);
    dec_cross_partial<<<dim3(8, 64), 256, 0, stream>>>(
        dqq, dec_qkv2_b + ((size_t)i * 3 + 0) * DM, kvf, kvf + ACTL, pm, pl, po);
    dec_cross_combine<<<64, 64, 0, stream>>>(pm, pl, po, da);
    add_ln<false><<<NB, 256, 0, stream>>>(
        da, dd, nullptr, dec_ln2_g + i * DM, dec_ln2_b + i * DM, dd, nullptr);
    skinny_splitk<false><<<dim3(32, 8), 256, 0, stream>>>(
        dd, nullptr, dec_ffn1_w + (size_t)i * WFS, dh, DFF, DM, 64);
    skinny_splitk<true><<<dim3(8, 32), 256, 0, stream>>>(
        dh, dec_ffn1_b + (size_t)i * DFF, dec_ffn2_w + (size_t)i * WFS,
        df, DM, DFF, 64);
    add_ln<false><<<NB, 256, 0, stream>>>(
        df, dd, dec_ffn2_b + (size_t)i * DM,
        dec_ln3_g + i * DM, dec_ln3_b + i * DM, dd, nullptr);
  }

  // ---- output projection ----
  init_out<<<(NB * OUTD + 255) / 256, 256, 0, stream>>>((float*)d_out, out_b);
  skinny_splitk<false><<<dim3(16, 16), 256, 0, stream>>>(
      dd, nullptr, out_w, (float*)d_out, OUTD, DM, 32);
}

// Round 6
// 1233.733 us; speedup vs baseline: 6.8875x; 1.0005x over previous
//
#include <hip/hip_runtime.h>
#include <hip/hip_bf16.h>

#define DM 512
#define NH 8
#define DK 64
#define SEQ 512
#define NB 8
#define NL 6
#define DFF 2048
#define OUTD 1000
#define EMB_SCALE 22.627416997969522f
#define PE_C (-0.017988946039015984)   // -ln(10000)/512

typedef __bf16 bf16x8 __attribute__((ext_vector_type(8)));
typedef __bf16 bf16x4 __attribute__((ext_vector_type(4)));
typedef float f32x4 __attribute__((ext_vector_type(4)));

__device__ __forceinline__ void load16_lds(const __bf16* g, __bf16* l) {
  __builtin_amdgcn_global_load_lds(
      (const __attribute__((address_space(1))) void*)g,
      (__attribute__((address_space(3))) void*)l, 16, 0, 0);
}

__device__ __forceinline__ float dot8(bf16x8 w, const float* a) {
  float s = 0.f;
#pragma unroll
  for (int j = 0; j < 8; ++j) s += (float)w[j] * a[j];
  return s;
}

// ---------------- PE table ----------------
__global__ __launch_bounds__(256) void pe_kernel(float* __restrict__ pe) {
  int s = blockIdx.x;
  int d2 = threadIdx.x;
  double div = exp((double)(2 * d2) * PE_C);
  double arg = (double)s * div;
  pe[(size_t)s * DM + 2 * d2] = (float)sin(arg);
  pe[(size_t)s * DM + 2 * d2 + 1] = (float)cos(arg);
}

// ---------------- embedding ----------------
__global__ __launch_bounds__(256) void embed_enc(const int* __restrict__ x,
                                                 const float* __restrict__ emb,
                                                 const float* __restrict__ pe,
                                                 float* __restrict__ e,
                                                 __bf16* __restrict__ eb) {
  int idx = blockIdx.x * 256 + threadIdx.x;
  int d = idx & (DM - 1);
  int bs = idx >> 9;
  int s = bs & (SEQ - 1);
  int tok = x[bs];
  float v = emb[(size_t)tok * DM + d] * EMB_SCALE + pe[(size_t)s * DM + d];
  e[idx] = v;
  eb[idx] = (__bf16)v;
}

__global__ __launch_bounds__(256) void embed_dec(const int* __restrict__ t,
                                                 const float* __restrict__ emb,
                                                 float* __restrict__ dd) {
  int idx = blockIdx.x * 256 + threadIdx.x;
  int d = idx & (DM - 1);
  int b = idx >> 9;
  float pe = (d & 1) ? 1.0f : 0.0f;
  dd[idx] = emb[(size_t)t[b] * DM + d] * EMB_SCALE + pe;
}

// ---------------- weight transpose fp32[K][N] -> bf16[N][K] ----------------
__global__ __launch_bounds__(256) void transpose_w(const float* __restrict__ W,
                                                   __bf16* __restrict__ WT,
                                                   int K, int N) {
  __shared__ float t[32][33];
  size_t off = (size_t)blockIdx.z * K * N;
  W += off; WT += off;
  int k0 = blockIdx.y * 32, n0 = blockIdx.x * 32;
  int tx = threadIdx.x & 7, ty = threadIdx.x >> 3;
  float4 v = *(const float4*)&W[(size_t)(k0 + ty) * N + n0 + tx * 4];
  t[ty][tx * 4 + 0] = v.x; t[ty][tx * 4 + 1] = v.y;
  t[ty][tx * 4 + 2] = v.z; t[ty][tx * 4 + 3] = v.w;
  __syncthreads();
  bf16x4 o;
  o[0] = (__bf16)t[tx * 4 + 0][ty];
  o[1] = (__bf16)t[tx * 4 + 1][ty];
  o[2] = (__bf16)t[tx * 4 + 2][ty];
  o[3] = (__bf16)t[tx * 4 + 3][ty];
  *(bf16x4*)&WT[(size_t)(n0 + ty) * K + k0 + tx * 4] = o;
}

// out_w fp32 [512][1000] -> bf16 [1000][512] (guarded tail)
__global__ __launch_bounds__(256) void transpose_ow(const float* __restrict__ W,
                                                    __bf16* __restrict__ WT) {
  __shared__ float t[32][33];
  int n0 = blockIdx.x * 32, k0 = blockIdx.y * 32;
  int tid = threadIdx.x;
  for (int i = tid; i < 1024; i += 256) {
    int kk = i >> 5, nn = i & 31;
    t[kk][nn] = (n0 + nn < OUTD) ? W[(size_t)(k0 + kk) * OUTD + n0 + nn] : 0.f;
  }
  __syncthreads();
  for (int i = tid; i < 1024; i += 256) {
    int nn = i >> 5, kk = i & 31;
    if (n0 + nn < OUTD)
      WT[(size_t)(n0 + nn) * DM + k0 + kk] = (__bf16)t[kk][nn];
  }
}

// ---------------- MFMA GEMM (global_load_lds staging, swizzled LDS) --------
template <int BN, bool RELU, bool WF32, bool WBF16, bool TRV, bool KVM>
__global__ __launch_bounds__(256) void mfma_gemm(
    const __bf16* __restrict__ A, const __bf16* __restrict__ BT,
    const float* __restrict__ bias, float* __restrict__ C,
    __bf16* __restrict__ Cb, __bf16* __restrict__ Vt, int M, int N, int K,
    long btStride, long bStride, long cStride) {
  int z = blockIdx.z;
  if (KVM) {
    long idx = (long)(z >> 1) * 3 + 1 + (z & 1);
    BT += idx * btStride;
    bias += idx * bStride;
  } else {
    BT += (size_t)z * btStride;
    bias += (size_t)z * bStride;
  }
  if (WF32) C += (size_t)z * cStride;
  if (WBF16) Cb += (size_t)z * cStride;

  constexpr int NI = BN / 32;
  __shared__ __bf16 As[128 * 64];
  __shared__ __bf16 Bs[BN * 64];

  int tid = threadIdx.x;
  int wave = tid >> 6, lane = tid & 63;
  int wm = wave >> 1, wn = wave & 1;
  int quad = lane >> 4, l16 = lane & 15;
  int rlane = lane >> 3, c8 = lane & 7;
  int m0 = blockIdx.y * 128, n0 = blockIdx.x * BN;
  int gcol = ((c8 ^ rlane) * 8);

  f32x4 acc[4][NI];
#pragma unroll
  for (int i = 0; i < 4; ++i)
#pragma unroll
    for (int j = 0; j < NI; ++j) acc[i][j] = (f32x4){0.f, 0.f, 0.f, 0.f};

  for (int k0 = 0; k0 < K; k0 += 64) {
    __syncthreads();
#pragma unroll
    for (int j = 0; j < 4; ++j) {
      int row = j * 32 + wave * 8 + rlane;
      load16_lds(&A[(size_t)(m0 + row) * K + k0 + gcol],
                 &As[(j * 32 + wave * 8) * 64]);
    }
#pragma unroll
    for (int j = 0; j < BN / 32; ++j) {
      int row = j * 32 + wave * 8 + rlane;
      load16_lds(&BT[(size_t)(n0 + row) * K + k0 + gcol],
                 &Bs[(j * 32 + wave * 8) * 64]);
    }
    __syncthreads();
#pragma unroll
    for (int kk = 0; kk < 64; kk += 32) {
      bf16x8 af[4], bf[NI];
#pragma unroll
      for (int i = 0; i < 4; ++i) {
        int row = wm * 64 + i * 16 + l16;
        af[i] = *(const bf16x8*)&As[row * 64 + ((((kk >> 3) + quad) ^ (row & 7)) * 8)];
      }
#pragma unroll
      for (int i = 0; i < NI; ++i) {
        int row = wn * (BN / 2) + i * 16 + l16;
        bf[i] = *(const bf16x8*)&Bs[row * 64 + ((((kk >> 3) + quad) ^ (row & 7)) * 8)];
      }
#pragma unroll
      for (int mi = 0; mi < 4; ++mi)
#pragma unroll
        for (int ni = 0; ni < NI; ++ni)
          acc[mi][ni] = __builtin_amdgcn_mfma_f32_16x16x32_bf16(
              af[mi], bf[ni], acc[mi][ni], 0, 0, 0);
    }
  }

#pragma unroll
  for (int ni = 0; ni < NI; ++ni) {
    int col = n0 + wn * (BN / 2) + ni * 16 + l16;
    float bv = bias[col];
    if (TRV && z == 2) {
      int b = m0 >> 9;
#pragma unroll
      for (int mi = 0; mi < 4; ++mi) {
        int srow = (m0 & 511) + wm * 64 + mi * 16 + quad * 4;
        bf16x4 pk;
#pragma unroll
        for (int r = 0; r < 4; ++r) pk[r] = (__bf16)(acc[mi][ni][r] + bv);
        *(bf16x4*)&Vt[((size_t)(b * 512 + col)) * 512 + srow] = pk;
      }
    } else {
#pragma unroll
      for (int mi = 0; mi < 4; ++mi) {
#pragma unroll
        for (int r = 0; r < 4; ++r) {
          int row = m0 + wm * 64 + mi * 16 + quad * 4 + r;
          float v = acc[mi][ni][r] + bv;
          if (RELU) v = fmaxf(v, 0.f);
          if (WF32) C[(size_t)row * N + col] = v;
          if (WBF16) Cb[(size_t)row * N + col] = (__bf16)v;
        }
      }
    }
  }
}

// ---------------- MFMA encoder attention (K natural, V pre-transposed) -----
#define SCP 520
__global__ __launch_bounds__(256) void attn_mfma(const __bf16* __restrict__ QKV,
                                                 const __bf16* __restrict__ Vt,
                                                 float* __restrict__ O) {
  __shared__ __bf16 Sc[16 * SCP];
  __shared__ __bf16 Tt[64 * 64];

  const long ACTL = (long)NB * SEQ * DM;
  int tid = threadIdx.x;
  int wave = tid >> 6, lane = tid & 63;
  int quad = lane >> 4, l16 = lane & 15;
  int rlane = lane >> 3, c8 = lane & 7;
  int q0 = blockIdx.x * 16;
  int bh = blockIdx.y, b = bh >> 3, h = bh & 7;
  const __bf16* Q = QKV;
  const __bf16* Kp = QKV + ACTL;
  size_t baseQ = ((size_t)b * SEQ + q0) * DM + h * DK;
  size_t baseK = ((size_t)b * SEQ) * DM + h * DK;
  const __bf16* VtB = Vt + ((size_t)(b * 512 + h * 64)) * 512;
  int gcol = (c8 ^ rlane) * 8;

  bf16x8 af0 = *(const bf16x8*)&Q[baseQ + (size_t)l16 * DM + quad * 8];
  bf16x8 af1 = *(const bf16x8*)&Q[baseQ + (size_t)l16 * DM + 32 + quad * 8];

  for (int kt = 0; kt < 8; ++kt) {
    __syncthreads();
#pragma unroll
    for (int j = 0; j < 2; ++j) {
      int row = j * 32 + wave * 8 + rlane;
      load16_lds(&Kp[baseK + (size_t)(kt * 64 + row) * DM + gcol],
                 &Tt[(j * 32 + wave * 8) * 64]);
    }
    __syncthreads();
    f32x4 acc = (f32x4){0.f, 0.f, 0.f, 0.f};
    int krow = wave * 16 + l16, sw = krow & 7;
    bf16x8 b0 = *(const bf16x8*)&Tt[krow * 64 + ((quad ^ sw) * 8)];
    bf16x8 b1 = *(const bf16x8*)&Tt[krow * 64 + (((4 + quad) ^ sw) * 8)];
    acc = __builtin_amdgcn_mfma_f32_16x16x32_bf16(af0, b0, acc, 0, 0, 0);
    acc = __builtin_amdgcn_mfma_f32_16x16x32_bf16(af1, b1, acc, 0, 0, 0);
#pragma unroll
    for (int r = 0; r < 4; ++r)
      Sc[(quad * 4 + r) * SCP + kt * 64 + wave * 16 + l16] =
          (__bf16)(acc[r] * 0.125f);
  }
  __syncthreads();

#pragma unroll
  for (int rr = 0; rr < 4; ++rr) {
    int r = wave * 4 + rr;
    float v[8];
    float mx = -1e30f;
#pragma unroll
    for (int j = 0; j < 8; ++j) {
      v[j] = (float)Sc[r * SCP + j * 64 + lane];
      mx = fmaxf(mx, v[j]);
    }
    for (int o = 32; o > 0; o >>= 1) mx = fmaxf(mx, __shfl_xor(mx, o));
    float sum = 0.f;
#pragma unroll
    for (int j = 0; j < 8; ++j) { v[j] = __expf(v[j] - mx); sum += v[j]; }
    for (int o = 32; o > 0; o >>= 1) sum += __shfl_xor(sum, o);
    float inv = 1.f / sum;
#pragma unroll
    for (int j = 0; j < 8; ++j)
      Sc[r * SCP + j * 64 + lane] = (__bf16)(v[j] * inv);
  }

  f32x4 oacc = (f32x4){0.f, 0.f, 0.f, 0.f};
  for (int kt = 0; kt < 8; ++kt) {
    __syncthreads();
#pragma unroll
    for (int j = 0; j < 2; ++j) {
      int row = j * 32 + wave * 8 + rlane;
      load16_lds(&VtB[(size_t)row * 512 + kt * 64 + gcol],
                 &Tt[(j * 32 + wave * 8) * 64]);
    }
    __syncthreads();
    int drow = wave * 16 + l16, sw = drow & 7;
#pragma unroll
    for (int kk = 0; kk < 64; kk += 32) {
      bf16x8 pa = *(const bf16x8*)&Sc[l16 * SCP + kt * 64 + kk + quad * 8];
      bf16x8 vb = *(const bf16x8*)&Tt[drow * 64 + ((((kk >> 3) + quad) ^ sw) * 8)];
      oacc = __builtin_amdgcn_mfma_f32_16x16x32_bf16(pa, vb, oacc, 0, 0, 0);
    }
  }
#pragma unroll
  for (int r = 0; r < 4; ++r)
    O[((size_t)b * SEQ + q0 + quad * 4 + r) * DM + h * DK + wave * 16 + l16] =
        oacc[r];
}

// ---------------- residual + layernorm ----------------
template <bool WB>
__global__ __launch_bounds__(256) void add_ln(
    const float* __restrict__ x, const float* __restrict__ res,
    const float* __restrict__ cbias,
    const float* __restrict__ g, const float* __restrict__ beta,
    float* __restrict__ y, __bf16* __restrict__ yb) {
  int row = blockIdx.x;
  int tid = threadIdx.x;
  const float* xr = x + (size_t)row * DM;
  const float* rr = res + (size_t)row * DM;
  float b0 = cbias ? cbias[tid] : 0.f;
  float b1 = cbias ? cbias[tid + 256] : 0.f;
  float v0 = xr[tid] + b0 + rr[tid];
  float v1 = xr[tid + 256] + b1 + rr[tid + 256];
  float s = v0 + v1, sq = v0 * v0 + v1 * v1;
  for (int o = 32; o > 0; o >>= 1) {
    s += __shfl_xor(s, o);
    sq += __shfl_xor(sq, o);
  }
  __shared__ float ps[4], pq[4];
  int wv = tid >> 6;
  if ((tid & 63) == 0) { ps[wv] = s; pq[wv] = sq; }
  __syncthreads();
  s = ps[0] + ps[1] + ps[2] + ps[3];
  sq = pq[0] + pq[1] + pq[2] + pq[3];
  float mean = s * (1.f / DM);
  float var = sq * (1.f / DM) - mean * mean;
  float rstd = rsqrtf(var + 1e-5f);
  float o0 = (v0 - mean) * rstd * g[tid] + beta[tid];
  float o1 = (v1 - mean) * rstd * g[tid + 256] + beta[tid + 256];
  y[(size_t)row * DM + tid] = o0;
  y[(size_t)row * DM + tid + 256] = o1;
  if (WB) {
    yb[(size_t)row * DM + tid] = (__bf16)o0;
    yb[(size_t)row * DM + tid + 256] = (__bf16)o1;
  }
}

// ============ fused decoder kernels (M = 8 rows) ============

// dd[r] = LN(dd[r] + dd[r] @ WvT^T + bv)  -- one block per row
__global__ __launch_bounds__(256) void dec_vln(
    float* __restrict__ dd, const __bf16* __restrict__ WvT,
    const float* __restrict__ bv, const float* __restrict__ g,
    const float* __restrict__ beta) {
  __shared__ float arow[DM];
  int r = blockIdx.x, tid = threadIdx.x;
  arow[tid] = dd[(size_t)r * DM + tid];
  arow[tid + 256] = dd[(size_t)r * DM + tid + 256];
  __syncthreads();
  float out[2];
#pragma unroll
  for (int cc = 0; cc < 2; ++cc) {
    int c = tid + cc * 256;
    const __bf16* w = &WvT[(size_t)c * DM];
    float acc = 0.f;
#pragma unroll 4
    for (int k = 0; k < DM; k += 8) acc += dot8(*(const bf16x8*)&w[k], &arow[k]);
    out[cc] = arow[c] + acc + bv[c];
  }
  float s = out[0] + out[1], sq = out[0] * out[0] + out[1] * out[1];
  for (int o = 32; o > 0; o >>= 1) { s += __shfl_xor(s, o); sq += __shfl_xor(sq, o); }
  __shared__ float ps[4], pq[4];
  int wv = tid >> 6;
  if ((tid & 63) == 0) { ps[wv] = s; pq[wv] = sq; }
  __syncthreads();
  s = ps[0] + ps[1] + ps[2] + ps[3];
  sq = pq[0] + pq[1] + pq[2] + pq[3];
  float mean = s * (1.f / DM);
  float rstd = rsqrtf(sq * (1.f / DM) - mean * mean + 1e-5f);
  dd[(size_t)r * DM + tid] = (out[0] - mean) * rstd * g[tid] + beta[tid];
  dd[(size_t)r * DM + tid + 256] = (out[1] - mean) * rstd * g[tid + 256] + beta[tid + 256];
}

// q = dd[b] @ Wq[:,h*64..] + bq; attention over 512 bf16 keys/values -> da
// one block per (b,h)
__global__ __launch_bounds__(256) void dec_qattn(
    const float* __restrict__ dd, const __bf16* __restrict__ WqT,
    const float* __restrict__ qb, const __bf16* __restrict__ Kb,
    const __bf16* __restrict__ Vb, float* __restrict__ da) {
  __shared__ float arow[DM];
  __shared__ float red[4][64];
  __shared__ float q[64];
  __shared__ float sc[SEQ];
  __shared__ float wred[4];
  __shared__ float smax, ssum;

  int bh = blockIdx.x, b = bh >> 3, h = bh & 7;
  int tid = threadIdx.x, lane = tid & 63, wave = tid >> 6;
  arow[tid] = dd[(size_t)b * DM + tid];
  arow[tid + 256] = dd[(size_t)b * DM + tid + 256];
  __syncthreads();

  // q-gemv: 64 cols x 4 k-subs
  {
    int c = tid & 63, s = tid >> 6;
    const __bf16* w = &WqT[(size_t)(h * 64 + c) * DM + s * 128];
    float acc = 0.f;
#pragma unroll
    for (int k = 0; k < 128; k += 8) acc += dot8(*(const bf16x8*)&w[k], &arow[s * 128 + k]);
    red[s][c] = acc;
  }
  __syncthreads();
  if (tid < 64) q[tid] = red[0][tid] + red[1][tid] + red[2][tid] + red[3][tid] + qb[h * 64 + tid];
  __syncthreads();

  // scores
  for (int key = tid; key < SEQ; key += 256) {
    const __bf16* kp = &Kb[((size_t)b * SEQ + key) * DM + h * 64];
    float acc = 0.f;
#pragma unroll
    for (int k = 0; k < 64; k += 8) acc += dot8(*(const bf16x8*)&kp[k], &q[k]);
    sc[key] = acc * 0.125f;
  }
  __syncthreads();
  float m = -1e30f;
  for (int j = tid; j < SEQ; j += 256) m = fmaxf(m, sc[j]);
  for (int o = 32; o > 0; o >>= 1) m = fmaxf(m, __shfl_xor(m, o));
  if (lane == 0) wred[wave] = m;
  __syncthreads();
  m = fmaxf(fmaxf(wred[0], wred[1]), fmaxf(wred[2], wred[3]));
  float sum = 0.f;
  for (int j = tid; j < SEQ; j += 256) {
    float p = __expf(sc[j] - m);
    sc[j] = p;
    sum += p;
  }
  for (int o = 32; o > 0; o >>= 1) sum += __shfl_xor(sum, o);
  __syncthreads();   // sc writes done before reuse of wred
  if (lane == 0) wred[wave] = sum;
  __syncthreads();
  float inv = 1.f / (wred[0] + wred[1] + wred[2] + wred[3]);

  // PV
  {
    int d = tid & 63, s = tid >> 6;
    float acc = 0.f;
    const __bf16* vp = &Vb[((size_t)b * SEQ + s * 128) * DM + h * 64 + d];
#pragma unroll 8
    for (int k = 0; k < 128; ++k) acc += sc[s * 128 + k] * (float)vp[(size_t)k * DM];
    red[s][d] = acc;
  }
  __syncthreads();
  if (tid < 64)
    da[(size_t)b * DM + h * 64 + tid] =
        (red[0][tid] + red[1][tid] + red[2][tid] + red[3][tid]) * inv;
}

// h[r][col] = relu(dd[r] @ W1T[col] + b1[col]); wave per col, 4 cols/block
__global__ __launch_bounds__(256) void dec_ffn1(
    const float* __restrict__ dd, const __bf16* __restrict__ W1T,
    const float* __restrict__ b1, float* __restrict__ h) {
  __shared__ float a[8][DM];
  int tid = threadIdx.x, lane = tid & 63, wave = tid >> 6;
  for (int i = tid; i < 8 * DM; i += 256) a[i >> 9][i & 511] = dd[i];
  __syncthreads();
  int col = blockIdx.x * 4 + wave;
  bf16x8 w = *(const bf16x8*)&W1T[(size_t)col * DM + lane * 8];
  float acc[8];
#pragma unroll
  for (int r = 0; r < 8; ++r) acc[r] = dot8(w, &a[r][lane * 8]);
#pragma unroll
  for (int r = 0; r < 8; ++r)
    for (int o = 32; o > 0; o >>= 1) acc[r] += __shfl_xor(acc[r], o);
  if (lane == 0) {
    float bb = b1[col];
#pragma unroll
    for (int r = 0; r < 8; ++r) h[(size_t)r * DFF + col] = fmaxf(acc[r] + bb, 0.f);
  }
}

// df[r][col] = h[r] @ W2T[col] + b2[col]; 2 cols/block, 2 waves per col
__global__ __launch_bounds__(256) void dec_ffn2(
    const float* __restrict__ h, const __bf16* __restrict__ W2T,
    const float* __restrict__ b2, float* __restrict__ df) {
  __shared__ float red[4][8];
  int tid = threadIdx.x, lane = tid & 63, wave = tid >> 6;
  int c = wave >> 1, half = wave & 1;
  int col = blockIdx.x * 2 + c;
  int k0 = half * 1024 + lane * 8;
  bf16x8 w0 = *(const bf16x8*)&W2T[(size_t)col * DFF + k0];
  bf16x8 w1 = *(const bf16x8*)&W2T[(size_t)col * DFF + k0 + 512];
  float acc[8];
#pragma unroll
  for (int r = 0; r < 8; ++r) {
    float4 h0a = *(const float4*)&h[(size_t)r * DFF + k0];
    float4 h0b = *(const float4*)&h[(size_t)r * DFF + k0 + 4];
    float4 h1a = *(const float4*)&h[(size_t)r * DFF + k0 + 512];
    float4 h1b = *(const float4*)&h[(size_t)r * DFF + k0 + 516];
    float hh0[8] = {h0a.x, h0a.y, h0a.z, h0a.w, h0b.x, h0b.y, h0b.z, h0b.w};
    float hh1[8] = {h1a.x, h1a.y, h1a.z, h1a.w, h1b.x, h1b.y, h1b.z, h1b.w};
    acc[r] = dot8(w0, hh0) + dot8(w1, hh1);
  }
#pragma unroll
  for (int r = 0; r < 8; ++r)
    for (int o = 32; o > 0; o >>= 1) acc[r] += __shfl_xor(acc[r], o);
  if (lane == 0) {
#pragma unroll
    for (int r = 0; r < 8; ++r) red[wave][r] = acc[r];
  }
  __syncthreads();
  if (tid < 16) {
    int cc = tid >> 3, r = tid & 7;
    int ocol = blockIdx.x * 2 + cc;
    df[(size_t)r * DM + ocol] =
        red[cc * 2][r] + red[cc * 2 + 1][r] + b2[ocol];
  }
}

// out[r][col] = dd[r] @ WoT[col] + ob[col]; wave per col, 4 cols/block
__global__ __launch_bounds__(256) void dec_out(
    const float* __restrict__ dd, const __bf16* __restrict__ WoT,
    const float* __restrict__ ob, float* __restrict__ out) {
  __shared__ float a[8][DM];
  int tid = threadIdx.x, lane = tid & 63, wave = tid >> 6;
  for (int i = tid; i < 8 * DM; i += 256) a[i >> 9][i & 511] = dd[i];
  __syncthreads();
  int col = blockIdx.x * 4 + wave;
  bf16x8 w = *(const bf16x8*)&WoT[(size_t)col * DM + lane * 8];
  float acc[8];
#pragma unroll
  for (int r = 0; r < 8; ++r) acc[r] = dot8(w, &a[r][lane * 8]);
#pragma unroll
  for (int r = 0; r < 8; ++r)
    for (int o = 32; o > 0; o >>= 1) acc[r] += __shfl_xor(acc[r], o);
  if (lane == 0) {
    float bb = ob[col];
#pragma unroll
    for (int r = 0; r < 8; ++r) out[(size_t)r * OUTD + col] = acc[r] + bb;
  }
}

// ---------------------------------------------------------------------------
extern "C" void kernel_launch(void* const* d_in, const int* in_sizes, int n_in,
                              void* d_out, int out_size, void* d_ws, size_t ws_size,
                              hipStream_t stream) {
  const int* x = (const int*)d_in[0];
  const int* target = (const int*)d_in[1];
  const float* in_emb = (const float*)d_in[2];
  const float* out_emb = (const float*)d_in[3];
  const float* enc_qkv_w = (const float*)d_in[4];
  const float* enc_qkv_b = (const float*)d_in[5];
  const float* enc_ln1_g = (const float*)d_in[6];
  const float* enc_ln1_b = (const float*)d_in[7];
  const float* enc_ffn1_w = (const float*)d_in[8];
  const float* enc_ffn1_b = (const float*)d_in[9];
  const float* enc_ffn2_w = (const float*)d_in[10];
  const float* enc_ffn2_b = (const float*)d_in[11];
  const float* enc_ln2_g = (const float*)d_in[12];
  const float* enc_ln2_b = (const float*)d_in[13];
  const float* dec_qkv1_w = (const float*)d_in[14];
  const float* dec_qkv1_b = (const float*)d_in[15];
  const float* dec_ln1_g = (const float*)d_in[16];
  const float* dec_ln1_b = (const float*)d_in[17];
  const float* dec_qkv2_w = (const float*)d_in[18];
  const float* dec_qkv2_b = (const float*)d_in[19];
  const float* dec_ln2_g = (const float*)d_in[20];
  const float* dec_ln2_b = (const float*)d_in[21];
  const float* dec_ffn1_w = (const float*)d_in[22];
  const float* dec_ffn1_b = (const float*)d_in[23];
  const float* dec_ffn2_w = (const float*)d_in[24];
  const float* dec_ffn2_b = (const float*)d_in[25];
  const float* dec_ln3_g = (const float*)d_in[26];
  const float* dec_ln3_b = (const float*)d_in[27];
  const float* out_w = (const float*)d_in[28];
  const float* out_b = (const float*)d_in[29];

  const long ACTL = (long)NB * SEQ * DM;           // 2M elems
  const int M = NB * SEQ;                           // 4096
  const long WQS = (long)DM * DM;
  const long WFS = (long)DM * DFF;

  char* p = (char*)d_ws;
  float* e = (float*)p;            p += ACTL * 4;
  float* tb = (float*)p;           p += ACTL * 4;
  float* pe = (float*)p;           p += (long)SEQ * DM * 4;
  float* dd = (float*)p;           p += NB * DM * 4;
  float* da = (float*)p;           p += NB * DM * 4;
  float* dh = (float*)p;           p += NB * DFF * 4;
  float* df = (float*)p;           p += NB * DM * 4;
  p = (char*)(((uintptr_t)p + 255) & ~(uintptr_t)255);
  __bf16* eb = (__bf16*)p;         p += ACTL * 2;
  __bf16* qkvb = (__bf16*)p;       p += 3 * ACTL * 2;   // Q,K; slice 2 = V^T
  __bf16* hbb = (__bf16*)p;        p += (long)M * DFF * 2;
  __bf16* kvb = (__bf16*)p;        p += 12L * ACTL * 2; // [layer][K,V][4096][512]
  __bf16* wtq = (__bf16*)p;        p += 18L * WQS * 2;
  __bf16* wtf1 = (__bf16*)p;       p += 6L * WFS * 2;
  __bf16* wtf2 = (__bf16*)p;       p += 6L * WFS * 2;
  __bf16* wtd = (__bf16*)p;        p += 18L * WQS * 2;  // dec_qkv2^T
  __bf16* wtd1 = (__bf16*)p;       p += 18L * WQS * 2;  // dec_qkv1^T
  __bf16* wf1t = (__bf16*)p;       p += 6L * WFS * 2;
  __bf16* wf2t = (__bf16*)p;       p += 6L * WFS * 2;
  __bf16* wot = (__bf16*)p;        p += (long)OUTD * DM * 2;

  __bf16* vtb = qkvb + 2 * ACTL;

  // ---- one-time prep ----
  pe_kernel<<<SEQ, 256, 0, stream>>>(pe);
  transpose_w<<<dim3(16, 16, 18), 256, 0, stream>>>(enc_qkv_w, wtq, DM, DM);
  transpose_w<<<dim3(64, 16, 6), 256, 0, stream>>>(enc_ffn1_w, wtf1, DM, DFF);
  transpose_w<<<dim3(16, 64, 6), 256, 0, stream>>>(enc_ffn2_w, wtf2, DFF, DM);
  transpose_w<<<dim3(16, 16, 18), 256, 0, stream>>>(dec_qkv2_w, wtd, DM, DM);
  transpose_w<<<dim3(16, 16, 18), 256, 0, stream>>>(dec_qkv1_w, wtd1, DM, DM);
  transpose_w<<<dim3(64, 16, 6), 256, 0, stream>>>(dec_ffn1_w, wf1t, DM, DFF);
  transpose_w<<<dim3(16, 64, 6), 256, 0, stream>>>(dec_ffn2_w, wf2t, DFF, DM);
  transpose_ow<<<dim3(32, 16), 256, 0, stream>>>(out_w, wot);

  // ---- encoder ----
  embed_enc<<<(M * DM) / 256, 256, 0, stream>>>(x, in_emb, pe, e, eb);
  for (int i = 0; i < NL; ++i) {
    mfma_gemm<128, false, false, true, true, false><<<dim3(4, 32, 3), 256, 0, stream>>>(
        eb, wtq + (size_t)i * 3 * WQS, enc_qkv_b + (size_t)i * 3 * DM,
        nullptr, qkvb, vtb, M, DM, DM, WQS, DM, ACTL);
    attn_mfma<<<dim3(SEQ / 16, NB * NH), 256, 0, stream>>>(qkvb, vtb, tb);
    add_ln<true><<<M, 256, 0, stream>>>(tb, e, nullptr, enc_ln1_g + i * DM,
                                        enc_ln1_b + i * DM, e, eb);
    mfma_gemm<128, true, false, true, false, false><<<dim3(16, 32, 1), 256, 0, stream>>>(
        eb, wtf1 + (size_t)i * WFS, enc_ffn1_b + (size_t)i * DFF,
        nullptr, hbb, nullptr, M, DFF, DM, 0, 0, 0);
    mfma_gemm<64, false, true, false, false, false><<<dim3(8, 32, 1), 256, 0, stream>>>(
        hbb, wtf2 + (size_t)i * WFS, enc_ffn2_b + (size_t)i * DM,
        tb, nullptr, nullptr, M, DM, DFF, 0, 0, 0);
    add_ln<true><<<M, 256, 0, stream>>>(tb, e, nullptr, enc_ln2_g + i * DM,
                                        enc_ln2_b + i * DM, e, eb);
  }

  // ---- cross K/V for all 6 layers in one dispatch (bf16 out) ----
  mfma_gemm<128, false, false, true, false, true><<<dim3(4, 32, 12), 256, 0, stream>>>(
      eb, wtd, dec_qkv2_b, nullptr, kvb, nullptr, M, DM, DM, WQS, DM, ACTL);

  // ---- decoder (seq len 1, fully fused, no atomics/memsets) ----
  embed_dec<<<(NB * DM) / 256, 256, 0, stream>>>(target, out_emb, dd);
  for (int i = 0; i < NL; ++i) {
    dec_vln<<<8, 256, 0, stream>>>(
        dd, wtd1 + ((size_t)i * 3 + 2) * WQS, dec_qkv1_b + ((size_t)i * 3 + 2) * DM,
        dec_ln1_g + i * DM, dec_ln1_b + i * DM);
    dec_qattn<<<64, 256, 0, stream>>>(
        dd, wtd + (size_t)i * 3 * WQS, dec_qkv2_b + (size_t)i * 3 * DM,
        kvb + (size_t)i * 2 * ACTL, kvb + ((size_t)i * 2 + 1) * ACTL, da);
    add_ln<false><<<NB, 256, 0, stream>>>(
        da, dd, nullptr, dec_ln2_g + i * DM, dec_ln2_b + i * DM, dd, nullptr);
    dec_ffn1<<<DFF / 4, 256, 0, stream>>>(
        dd, wf1t + (size_t)i * WFS, dec_ffn1_b + (size_t)i * DFF, dh);
    dec_ffn2<<<DM / 2, 256, 0, stream>>>(
        dh, wf2t + (size_t)i * WFS, dec_ffn2_b + (size_t)i * DM, df);
    add_ln<false><<<NB, 256, 0, stream>>>(
        df, dd, nullptr, dec_ln3_g + i * DM, dec_ln3_b + i * DM, dd, nullptr);
  }

  // ---- output projection (direct, bias fused) ----
  dec_out<<<OUTD / 4, 256, 0, stream>>>(dd, wot, out_b, (float*)d_out);
}